// Round 1
// baseline (5041.647 us; speedup 1.0000x reference)
//
#include <hip/hip_runtime.h>

static inline int ceil_div(int a, int b) { return (a + b - 1) / b; }

// ---------------- CSR build ----------------
__global__ __launch_bounds__(256) void count_deg_k(const int* __restrict__ edges,
                                                   int* __restrict__ deg, int E) {
    int e = blockIdx.x * blockDim.x + threadIdx.x;
    if (e < E) {
        atomicAdd(&deg[edges[2 * e]], 1);
        atomicAdd(&deg[edges[2 * e + 1]], 1);
    }
}

__global__ __launch_bounds__(1024) void scan_k(const int* __restrict__ deg,
                                               int* __restrict__ rowptr,
                                               int* __restrict__ cursor, int Nv) {
    __shared__ int s[1024];
    __shared__ int carry;
    int tid = threadIdx.x;
    if (tid == 0) carry = 0;
    __syncthreads();
    for (int base = 0; base < Nv; base += 1024) {
        int i = base + tid;
        int v = (i < Nv) ? deg[i] : 0;
        s[tid] = v;
        __syncthreads();
        for (int off = 1; off < 1024; off <<= 1) {
            int t = (tid >= off) ? s[tid - off] : 0;
            __syncthreads();
            if (tid >= off) s[tid] += t;
            __syncthreads();
        }
        int incl = s[tid];
        int total = s[1023];
        int excl = incl - v + carry;
        if (i < Nv) { rowptr[i] = excl; cursor[i] = excl; }
        __syncthreads();
        if (tid == 0) carry += total;
        __syncthreads();
    }
    if (tid == 0) rowptr[Nv] = carry;
}

__global__ __launch_bounds__(256) void fill_adj_k(const int* __restrict__ edges,
                                                  int* __restrict__ cursor,
                                                  int* __restrict__ adj, int E) {
    int e = blockIdx.x * blockDim.x + threadIdx.x;
    if (e < E) {
        int a = edges[2 * e], b = edges[2 * e + 1];
        adj[atomicAdd(&cursor[a], 1)] = b;
        adj[atomicAdd(&cursor[b], 1)] = a;
    }
}

// ---------------- enc @ g0_w*[131:387] (per-batch constant) ----------------
__global__ __launch_bounds__(128) void enc_proj_k(const float* __restrict__ enc,
                                                  const float* __restrict__ w0,
                                                  const float* __restrict__ w1,
                                                  float* __restrict__ out, int B_) {
    int b = blockIdx.x, sH = blockIdx.y, j = threadIdx.x;
    const float* w = sH ? w1 : w0;
    const float* eb = enc + b * 256;
    float acc = 0.f;
    for (int c = 0; c < 256; ++c) acc = fmaf(eb[c], w[(131 + c) * 128 + j], acc);
    out[(sH * B_ + b) * 128 + j] = acc;
}

// ---------------- pixel projection: pp[b][p][j] = sum_c fm[b][c][p] * W[c][j] ----------------
__global__ __launch_bounds__(256) void gemm_proj_k(const float* __restrict__ fm,
                                                   const float* __restrict__ W,
                                                   float* __restrict__ pp, int C, int HW) {
    __shared__ float Xs[32][64];
    __shared__ float Ws[32][128];
    int tid = threadIdx.x;
    int p0 = blockIdx.x * 64;
    int b = blockIdx.y;
    const float* fmb = fm + (size_t)b * C * HW;
    float acc[8][4];
#pragma unroll
    for (int i = 0; i < 8; i++)
#pragma unroll
        for (int j = 0; j < 4; j++) acc[i][j] = 0.f;

    bool vec_ok = ((HW & 3) == 0);
    for (int kc = 0; kc < C; kc += 32) {
        {
            int p4 = (tid & 15) * 4;
            int k0 = tid >> 4;  // 0..15
#pragma unroll
            for (int kk = 0; kk < 32; kk += 16) {
                int k = k0 + kk;
                const float* src = fmb + (size_t)(kc + k) * HW + p0 + p4;
                float4 v;
                if (vec_ok && (p0 + p4 + 3 < HW)) {
                    v = *(const float4*)src;
                } else {
                    v.x = (p0 + p4 + 0 < HW) ? src[0] : 0.f;
                    v.y = (p0 + p4 + 1 < HW) ? src[1] : 0.f;
                    v.z = (p0 + p4 + 2 < HW) ? src[2] : 0.f;
                    v.w = (p0 + p4 + 3 < HW) ? src[3] : 0.f;
                }
                *(float4*)&Xs[k][p4] = v;
            }
        }
        {
            int j4 = (tid & 31) * 4;
            int k0 = tid >> 5;  // 0..7
#pragma unroll
            for (int kk = 0; kk < 32; kk += 8) {
                int k = k0 + kk;
                *(float4*)&Ws[k][j4] = *(const float4*)(W + (size_t)(kc + k) * 128 + j4);
            }
        }
        __syncthreads();
        int rb = (tid >> 5) * 8;
        int cb = (tid & 31) * 4;
#pragma unroll
        for (int k = 0; k < 32; ++k) {
            float xr[8], wc[4];
#pragma unroll
            for (int i = 0; i < 8; i++) xr[i] = Xs[k][rb + i];
#pragma unroll
            for (int j = 0; j < 4; j++) wc[j] = Ws[k][cb + j];
#pragma unroll
            for (int i = 0; i < 8; i++)
#pragma unroll
                for (int j = 0; j < 4; j++) acc[i][j] = fmaf(xr[i], wc[j], acc[i][j]);
        }
        __syncthreads();
    }
    int rb = (tid >> 5) * 8;
    int cb = (tid & 31) * 4;
#pragma unroll
    for (int i = 0; i < 8; i++) {
        int p = p0 + rb + i;
        if (p < HW) {
            float4 v = make_float4(acc[i][0], acc[i][1], acc[i][2], acc[i][3]);
            *(float4*)(pp + ((size_t)b * HW + p) * 128 + cb) = v;
        }
    }
}

// ---------------- bilinear sample in projected space + bottleneck bias/relu + layer0 pre-bias ----------------
__device__ __forceinline__ float sample_level(const float* __restrict__ pp, int Hh, int Ww,
                                              float gx, float gy, int j) {
    float x = (gx + 1.f) * 0.5f * (float)(Ww - 1);
    float y = (gy + 1.f) * 0.5f * (float)(Hh - 1);
    float x0f = floorf(x), y0f = floorf(y);
    float wx1 = x - x0f, wy1 = y - y0f;
    float wx0 = 1.f - wx1, wy0 = 1.f - wy1;
    int x0 = (int)fminf(fmaxf(x0f, 0.f), (float)(Ww - 1));
    int x1 = (int)fminf(fmaxf(x0f + 1.f, 0.f), (float)(Ww - 1));
    int y0 = (int)fminf(fmaxf(y0f, 0.f), (float)(Hh - 1));
    int y1 = (int)fminf(fmaxf(y0f + 1.f, 0.f), (float)(Hh - 1));
    const float* r00 = pp + (size_t)(y0 * Ww + x0) * 128;
    const float* r01 = pp + (size_t)(y0 * Ww + x1) * 128;
    const float* r10 = pp + (size_t)(y1 * Ww + x0) * 128;
    const float* r11 = pp + (size_t)(y1 * Ww + x1) * 128;
    return wy0 * (wx0 * r00[j] + wx1 * r01[j]) + wy1 * (wx0 * r10[j] + wx1 * r11[j]);
}

__global__ __launch_bounds__(128) void sample_bottleneck_k(
    const float* __restrict__ av, const float* __restrict__ pp1, const float* __restrict__ pp2,
    const float* __restrict__ pp3, const float* __restrict__ pp4, const float* __restrict__ bb,
    const float* __restrict__ verts, const float* __restrict__ encp,
    const float* __restrict__ g0w0, const float* __restrict__ g0w1, float* __restrict__ X,
    float* __restrict__ H, int V_, int B_) {
    int n = blockIdx.x, j = threadIdx.x;
    int b = n / V_;
    float gx = av[(size_t)n * 3 + 0];
    float gy = av[(size_t)n * 3 + 1];
    float acc = bb[j];
    acc += sample_level(pp1 + (size_t)b * 3136 * 128, 56, 56, gx, gy, j);
    acc += sample_level(pp2 + (size_t)b * 784 * 128, 28, 28, gx, gy, j);
    acc += sample_level(pp3 + (size_t)b * 196 * 128, 14, 14, gx, gy, j);
    acc += sample_level(pp4 + (size_t)b * 49 * 128, 7, 7, gx, gy, j);
    X[(size_t)n * 128 + j] = fmaxf(acc, 0.f);
    float v0 = verts[n * 3 + 0], v1 = verts[n * 3 + 1], v2 = verts[n * 3 + 2];
    H[(size_t)n * 256 + j] = encp[(0 * B_ + b) * 128 + j] + v0 * g0w0[128 * 128 + j] +
                             v1 * g0w0[129 * 128 + j] + v2 * g0w0[130 * 128 + j];
    H[(size_t)n * 256 + 128 + j] = encp[(1 * B_ + b) * 128 + j] + v0 * g0w1[128 * 128 + j] +
                                   v1 * g0w1[129 * 128 + j] + v2 * g0w1[130 * 128 + j];
}

// ---------------- layer GEMM: H[n][0:128]=X@W0+b0 (+pre), H[n][128:256]=X@W1+b1 (+pre) ----------------
__global__ __launch_bounds__(256) void gemm_layer_k(const float* __restrict__ X,
                                                    const float* __restrict__ W0,
                                                    const float* __restrict__ W1,
                                                    const float* __restrict__ b0,
                                                    const float* __restrict__ b1,
                                                    float* __restrict__ H, int M,
                                                    int accumulate) {
    __shared__ float Xs[32][68];
    __shared__ float Ws[32][256];
    int tid = threadIdx.x;
    int m0 = blockIdx.x * 64;
    float acc[8][8];
#pragma unroll
    for (int i = 0; i < 8; i++)
#pragma unroll
        for (int j = 0; j < 8; j++) acc[i][j] = 0.f;

#pragma unroll
    for (int kc = 0; kc < 128; kc += 32) {
        {
            int kq = (tid & 7) * 4;
            int r0 = tid >> 3;  // 0..31
#pragma unroll
            for (int rr = 0; rr < 64; rr += 32) {
                int r = r0 + rr;
                int gm = m0 + r;
                float4 v = make_float4(0.f, 0.f, 0.f, 0.f);
                if (gm < M) v = *(const float4*)(X + (size_t)gm * 128 + kc + kq);
                Xs[kq + 0][r] = v.x;
                Xs[kq + 1][r] = v.y;
                Xs[kq + 2][r] = v.z;
                Xs[kq + 3][r] = v.w;
            }
        }
        {
            int j4 = (tid & 63) * 4;
            int k0 = tid >> 6;  // 0..3
            const float* wsrc = (j4 < 128) ? (W0 + j4) : (W1 + (j4 - 128));
#pragma unroll
            for (int kk = 0; kk < 32; kk += 4) {
                int k = k0 + kk;
                *(float4*)&Ws[k][j4] = *(const float4*)(wsrc + (size_t)(kc + k) * 128);
            }
        }
        __syncthreads();
        int rb = (tid >> 5) * 8;
        int cb = (tid & 31) * 8;
#pragma unroll
        for (int k = 0; k < 32; ++k) {
            float xr[8], wc[8];
#pragma unroll
            for (int i = 0; i < 8; i++) xr[i] = Xs[k][rb + i];
#pragma unroll
            for (int j = 0; j < 8; j++) wc[j] = Ws[k][cb + j];
#pragma unroll
            for (int i = 0; i < 8; i++)
#pragma unroll
                for (int j = 0; j < 8; j++) acc[i][j] = fmaf(xr[i], wc[j], acc[i][j]);
        }
        __syncthreads();
    }

    int rb = (tid >> 5) * 8;
    int cb = (tid & 31) * 8;
    const float* bp = (cb < 128) ? (b0 + cb) : (b1 + cb - 128);
    float bias[8];
#pragma unroll
    for (int j = 0; j < 8; j++) bias[j] = bp[j];
#pragma unroll
    for (int i = 0; i < 8; i++) {
        int gm = m0 + rb + i;
        if (gm < M) {
            size_t base = (size_t)gm * 256 + cb;
#pragma unroll
            for (int j0 = 0; j0 < 8; j0 += 4) {
                float4 v;
                v.x = acc[i][j0 + 0] + bias[j0 + 0];
                v.y = acc[i][j0 + 1] + bias[j0 + 1];
                v.z = acc[i][j0 + 2] + bias[j0 + 2];
                v.w = acc[i][j0 + 3] + bias[j0 + 3];
                if (accumulate) {
                    float4 h = *(const float4*)(H + base + j0);
                    v.x += h.x;
                    v.y += h.y;
                    v.z += h.z;
                    v.w += h.w;
                }
                *(float4*)(H + base + j0) = v;
            }
        }
    }
}

// ---------------- CSR gather aggregation + relu ----------------
__global__ __launch_bounds__(128) void agg_relu_k(const float* __restrict__ H,
                                                  const int* __restrict__ rowptr,
                                                  const int* __restrict__ adj,
                                                  float* __restrict__ Xo, int Nv) {
    int n = blockIdx.x;
    int j = threadIdx.x;
    float acc = H[(size_t)n * 256 + j];
    int s = rowptr[n], e = rowptr[n + 1];
    for (int t = s; t < e; ++t) {
        int nb = adj[t];
        acc += H[(size_t)nb * 256 + 128 + j];
    }
    Xo[(size_t)n * 128 + j] = fmaxf(acc, 0.f);
}

// ---------------- head: out = X @ off_w + off_b ----------------
__global__ __launch_bounds__(128) void final_out_k(const float* __restrict__ X,
                                                   const float* __restrict__ off_w,
                                                   const float* __restrict__ off_b,
                                                   float* __restrict__ out, int Nv) {
    __shared__ float s0[128], s1[128], s2[128];
    int n = blockIdx.x, k = threadIdx.x;
    float x = X[(size_t)n * 128 + k];
    s0[k] = x * off_w[k * 3 + 0];
    s1[k] = x * off_w[k * 3 + 1];
    s2[k] = x * off_w[k * 3 + 2];
    __syncthreads();
    for (int off = 64; off > 0; off >>= 1) {
        if (k < off) {
            s0[k] += s0[k + off];
            s1[k] += s1[k + off];
            s2[k] += s2[k + off];
        }
        __syncthreads();
    }
    if (k == 0) {
        out[n * 3 + 0] = s0[0] + off_b[0];
        out[n * 3 + 1] = s1[0] + off_b[1];
        out[n * 3 + 2] = s2[0] + off_b[2];
    }
}

extern "C" void kernel_launch(void* const* d_in, const int* in_sizes, int n_in, void* d_out,
                              int out_size, void* d_ws, size_t ws_size, hipStream_t stream) {
    const float* feat1 = (const float*)d_in[0];
    const float* feat2 = (const float*)d_in[1];
    const float* feat3 = (const float*)d_in[2];
    const float* feat4 = (const float*)d_in[3];
    const float* av = (const float*)d_in[4];
    const float* verts = (const float*)d_in[5];
    const float* image_enc = (const float*)d_in[6];
    const int* edges = (const int*)d_in[7];
    const float* bw = (const float*)d_in[8];
    const float* bb = (const float*)d_in[9];
    const float* g0w0 = (const float*)d_in[10];
    const float* g0b0 = (const float*)d_in[11];
    const float* g0w1 = (const float*)d_in[12];
    const float* g0b1 = (const float*)d_in[13];
    const float* gw0 = (const float*)d_in[14];
    const float* gb0 = (const float*)d_in[15];
    const float* gw1 = (const float*)d_in[16];
    const float* gb1 = (const float*)d_in[17];
    const float* off_w = (const float*)d_in[18];
    const float* off_b = (const float*)d_in[19];

    int B_ = in_sizes[6] / 256;       // 4
    int N_ = in_sizes[5] / 3;         // 40968
    int V_ = N_ / B_;                 // 10242
    int E_ = in_sizes[7] / 2;         // 122880

    char* wsb = (char*)d_ws;
    size_t off = 0;
    auto alloc = [&](size_t bytes) -> void* {
        void* p = (void*)(wsb + off);
        off += (bytes + 255) & ~(size_t)255;
        return p;
    };
    float* pp1 = (float*)alloc((size_t)B_ * 3136 * 128 * 4);
    float* pp2 = (float*)alloc((size_t)B_ * 784 * 128 * 4);
    float* pp3 = (float*)alloc((size_t)B_ * 196 * 128 * 4);
    float* pp4 = (float*)alloc((size_t)B_ * 49 * 128 * 4);
    float* XA = (float*)alloc((size_t)N_ * 128 * 4);
    float* XB = (float*)alloc((size_t)N_ * 128 * 4);
    float* Hb = (float*)alloc((size_t)N_ * 256 * 4);
    float* encp = (float*)alloc((size_t)2 * B_ * 128 * 4);
    int* deg = (int*)alloc((size_t)(N_ + 1) * 4);
    int* rowptr = (int*)alloc((size_t)(N_ + 1) * 4);
    int* cursor = (int*)alloc((size_t)N_ * 4);
    int* adj = (int*)alloc((size_t)2 * E_ * 4);

    // CSR build (edges fixed per call, rebuilt every call)
    hipMemsetAsync(deg, 0, (N_ + 1) * sizeof(int), stream);
    count_deg_k<<<ceil_div(E_, 256), 256, 0, stream>>>(edges, deg, E_);
    scan_k<<<1, 1024, 0, stream>>>(deg, rowptr, cursor, N_);
    fill_adj_k<<<ceil_div(E_, 256), 256, 0, stream>>>(edges, cursor, adj, E_);

    // per-batch enc projection for layer 0
    enc_proj_k<<<dim3(B_, 2), 128, 0, stream>>>(image_enc, g0w0, g0w1, encp, B_);

    // pixel projections (bilinear commutes with linear projection)
    gemm_proj_k<<<dim3(49, B_), 256, 0, stream>>>(feat1, bw + 0 * 128, pp1, 256, 3136);
    gemm_proj_k<<<dim3(13, B_), 256, 0, stream>>>(feat2, bw + 256 * 128, pp2, 512, 784);
    gemm_proj_k<<<dim3(4, B_), 256, 0, stream>>>(feat3, bw + 768 * 128, pp3, 1024, 196);
    gemm_proj_k<<<dim3(1, B_), 256, 0, stream>>>(feat4, bw + 1792 * 128, pp4, 2048, 49);

    // sample + bottleneck bias/relu -> XA ; layer0 pre-bias (verts + enc terms) -> Hb
    sample_bottleneck_k<<<N_, 128, 0, stream>>>(av, pp1, pp2, pp3, pp4, bb, verts, encp, g0w0,
                                                g0w1, XA, Hb, V_, B_);

    int gblocks = ceil_div(N_, 64);
    // layer 0 (accumulate pre-bias already in Hb)
    gemm_layer_k<<<gblocks, 256, 0, stream>>>(XA, g0w0, g0w1, g0b0, g0b1, Hb, N_, 1);
    agg_relu_k<<<N_, 128, 0, stream>>>(Hb, rowptr, adj, XB, N_);

    float* Xc = XB;
    float* Xn = XA;
    for (int i = 0; i < 7; ++i) {
        gemm_layer_k<<<gblocks, 256, 0, stream>>>(Xc, gw0 + (size_t)i * 16384,
                                                  gw1 + (size_t)i * 16384, gb0 + i * 128,
                                                  gb1 + i * 128, Hb, N_, 0);
        agg_relu_k<<<N_, 128, 0, stream>>>(Hb, rowptr, adj, Xn, N_);
        float* t = Xc;
        Xc = Xn;
        Xn = t;
    }

    final_out_k<<<N_, 128, 0, stream>>>(Xc, off_w, off_b, (float*)d_out, N_);
}

// Round 2
// 1289.657 us; speedup vs baseline: 3.9093x; 3.9093x over previous
//
#include <hip/hip_runtime.h>

static inline int ceil_div(int a, int b) { return (a + b - 1) / b; }

// ---------------- CSR build ----------------
__global__ __launch_bounds__(256) void count_deg_k(const int* __restrict__ edges,
                                                   int* __restrict__ deg, int E) {
    int e = blockIdx.x * blockDim.x + threadIdx.x;
    if (e < E) {
        atomicAdd(&deg[edges[2 * e]], 1);
        atomicAdd(&deg[edges[2 * e + 1]], 1);
    }
}

__global__ __launch_bounds__(1024) void scan_k(const int* __restrict__ deg,
                                               int* __restrict__ rowptr,
                                               int* __restrict__ cursor, int Nv) {
    __shared__ int s[1024];
    __shared__ int carry;
    int tid = threadIdx.x;
    if (tid == 0) carry = 0;
    __syncthreads();
    for (int base = 0; base < Nv; base += 1024) {
        int i = base + tid;
        int v = (i < Nv) ? deg[i] : 0;
        s[tid] = v;
        __syncthreads();
        for (int off = 1; off < 1024; off <<= 1) {
            int t = (tid >= off) ? s[tid - off] : 0;
            __syncthreads();
            if (tid >= off) s[tid] += t;
            __syncthreads();
        }
        int incl = s[tid];
        int total = s[1023];
        int excl = incl - v + carry;
        if (i < Nv) { rowptr[i] = excl; cursor[i] = excl; }
        __syncthreads();
        if (tid == 0) carry += total;
        __syncthreads();
    }
    if (tid == 0) rowptr[Nv] = carry;
}

__global__ __launch_bounds__(256) void fill_adj_k(const int* __restrict__ edges,
                                                  int* __restrict__ cursor,
                                                  int* __restrict__ adj, int E) {
    int e = blockIdx.x * blockDim.x + threadIdx.x;
    if (e < E) {
        int a = edges[2 * e], b = edges[2 * e + 1];
        adj[atomicAdd(&cursor[a], 1)] = b;
        adj[atomicAdd(&cursor[b], 1)] = a;
    }
}

// ---------------- enc @ g0_w*[131:387] (per-batch constant) ----------------
__global__ __launch_bounds__(128) void enc_proj_k(const float* __restrict__ enc,
                                                  const float* __restrict__ w0,
                                                  const float* __restrict__ w1,
                                                  float* __restrict__ out, int B_) {
    int b = blockIdx.x, sH = blockIdx.y, j = threadIdx.x;
    const float* w = sH ? w1 : w0;
    const float* eb = enc + b * 256;
    float acc = 0.f;
    for (int c = 0; c < 256; ++c) acc = fmaf(eb[c], w[(131 + c) * 128 + j], acc);
    out[(sH * B_ + b) * 128 + j] = acc;
}

// ---------------- pixel projection: pp[b][p][j] = sum_c fm[b][c][p] * W[c][j] ----------------
__global__ __launch_bounds__(256) void gemm_proj_k(const float* __restrict__ fm,
                                                   const float* __restrict__ W,
                                                   float* __restrict__ pp, int C, int HW) {
    __shared__ float Xs[32][64];
    __shared__ float Ws[32][128];
    int tid = threadIdx.x;
    int p0 = blockIdx.x * 64;
    int b = blockIdx.y;
    const float* fmb = fm + (size_t)b * C * HW;
    float acc[8][4];
#pragma unroll
    for (int i = 0; i < 8; i++)
#pragma unroll
        for (int j = 0; j < 4; j++) acc[i][j] = 0.f;

    bool vec_ok = ((HW & 3) == 0);
    for (int kc = 0; kc < C; kc += 32) {
        {
            int p4 = (tid & 15) * 4;
            int k0 = tid >> 4;  // 0..15
#pragma unroll
            for (int kk = 0; kk < 32; kk += 16) {
                int k = k0 + kk;
                const float* src = fmb + (size_t)(kc + k) * HW + p0 + p4;
                float4 v;
                if (vec_ok && (p0 + p4 + 3 < HW)) {
                    v = *(const float4*)src;
                } else {
                    v.x = (p0 + p4 + 0 < HW) ? src[0] : 0.f;
                    v.y = (p0 + p4 + 1 < HW) ? src[1] : 0.f;
                    v.z = (p0 + p4 + 2 < HW) ? src[2] : 0.f;
                    v.w = (p0 + p4 + 3 < HW) ? src[3] : 0.f;
                }
                *(float4*)&Xs[k][p4] = v;
            }
        }
        {
            int j4 = (tid & 31) * 4;
            int k0 = tid >> 5;  // 0..7
#pragma unroll
            for (int kk = 0; kk < 32; kk += 8) {
                int k = k0 + kk;
                *(float4*)&Ws[k][j4] = *(const float4*)(W + (size_t)(kc + k) * 128 + j4);
            }
        }
        __syncthreads();
        int rb = (tid >> 5) * 8;
        int cb = (tid & 31) * 4;
#pragma unroll 8
        for (int k = 0; k < 32; ++k) {
            float xr[8], wc[4];
#pragma unroll
            for (int i = 0; i < 8; i++) xr[i] = Xs[k][rb + i];
#pragma unroll
            for (int j = 0; j < 4; j++) wc[j] = Ws[k][cb + j];
#pragma unroll
            for (int i = 0; i < 8; i++)
#pragma unroll
                for (int j = 0; j < 4; j++) acc[i][j] = fmaf(xr[i], wc[j], acc[i][j]);
        }
        __syncthreads();
    }
    int rb = (tid >> 5) * 8;
    int cb = (tid & 31) * 4;
#pragma unroll
    for (int i = 0; i < 8; i++) {
        int p = p0 + rb + i;
        if (p < HW) {
            float4 v = make_float4(acc[i][0], acc[i][1], acc[i][2], acc[i][3]);
            *(float4*)(pp + ((size_t)b * HW + p) * 128 + cb) = v;
        }
    }
}

// ---------------- bilinear sample in projected space + bottleneck bias/relu + layer0 pre-bias ----------------
__device__ __forceinline__ float sample_level(const float* __restrict__ pp, int Hh, int Ww,
                                              float gx, float gy, int j) {
    float x = (gx + 1.f) * 0.5f * (float)(Ww - 1);
    float y = (gy + 1.f) * 0.5f * (float)(Hh - 1);
    float x0f = floorf(x), y0f = floorf(y);
    float wx1 = x - x0f, wy1 = y - y0f;
    float wx0 = 1.f - wx1, wy0 = 1.f - wy1;
    int x0 = (int)fminf(fmaxf(x0f, 0.f), (float)(Ww - 1));
    int x1 = (int)fminf(fmaxf(x0f + 1.f, 0.f), (float)(Ww - 1));
    int y0 = (int)fminf(fmaxf(y0f, 0.f), (float)(Hh - 1));
    int y1 = (int)fminf(fmaxf(y0f + 1.f, 0.f), (float)(Hh - 1));
    const float* r00 = pp + (size_t)(y0 * Ww + x0) * 128;
    const float* r01 = pp + (size_t)(y0 * Ww + x1) * 128;
    const float* r10 = pp + (size_t)(y1 * Ww + x0) * 128;
    const float* r11 = pp + (size_t)(y1 * Ww + x1) * 128;
    return wy0 * (wx0 * r00[j] + wx1 * r01[j]) + wy1 * (wx0 * r10[j] + wx1 * r11[j]);
}

__global__ __launch_bounds__(128) void sample_bottleneck_k(
    const float* __restrict__ av, const float* __restrict__ pp1, const float* __restrict__ pp2,
    const float* __restrict__ pp3, const float* __restrict__ pp4, const float* __restrict__ bb,
    const float* __restrict__ verts, const float* __restrict__ encp,
    const float* __restrict__ g0w0, const float* __restrict__ g0w1, float* __restrict__ X,
    float* __restrict__ H, int V_, int B_) {
    int n = blockIdx.x, j = threadIdx.x;
    int b = n / V_;
    float gx = av[(size_t)n * 3 + 0];
    float gy = av[(size_t)n * 3 + 1];
    float acc = bb[j];
    acc += sample_level(pp1 + (size_t)b * 3136 * 128, 56, 56, gx, gy, j);
    acc += sample_level(pp2 + (size_t)b * 784 * 128, 28, 28, gx, gy, j);
    acc += sample_level(pp3 + (size_t)b * 196 * 128, 14, 14, gx, gy, j);
    acc += sample_level(pp4 + (size_t)b * 49 * 128, 7, 7, gx, gy, j);
    X[(size_t)n * 128 + j] = fmaxf(acc, 0.f);
    float v0 = verts[n * 3 + 0], v1 = verts[n * 3 + 1], v2 = verts[n * 3 + 2];
    H[(size_t)n * 256 + j] = encp[(0 * B_ + b) * 128 + j] + v0 * g0w0[128 * 128 + j] +
                             v1 * g0w0[129 * 128 + j] + v2 * g0w0[130 * 128 + j];
    H[(size_t)n * 256 + 128 + j] = encp[(1 * B_ + b) * 128 + j] + v0 * g0w1[128 * 128 + j] +
                                   v1 * g0w1[129 * 128 + j] + v2 * g0w1[130 * 128 + j];
}

// ---------------- layer GEMM (no-spill rewrite) ----------------
// Block tile: 64 rows x 128 cols. grid.y in {0,1} selects (W0,b0) vs (W1,b1);
// output goes to H[n][yb*128 .. yb*128+127]. 256 threads, 8x4 acc each.
// Xs staged untransposed [row][k] -> inner reads Xs[rb+i][k] are per-half-wave
// uniform (broadcast, free). Ws[k][j] read as float4 stride-free.
__global__ __launch_bounds__(256, 4) void gemm_layer_k(const float* __restrict__ X,
                                                       const float* __restrict__ W0,
                                                       const float* __restrict__ W1,
                                                       const float* __restrict__ b0,
                                                       const float* __restrict__ b1,
                                                       float* __restrict__ H, int M,
                                                       int accumulate) {
    __shared__ float Xs[64][36];   // K-chunk 32, pad to 36 (16B-aligned rows)
    __shared__ float Ws[32][128];
    int tid = threadIdx.x;
    int m0 = blockIdx.x * 64;
    int yb = blockIdx.y;
    const float* W = yb ? W1 : W0;
    const float* bp = yb ? b1 : b0;

    float acc[8][4];
#pragma unroll
    for (int i = 0; i < 8; i++)
#pragma unroll
        for (int j = 0; j < 4; j++) acc[i][j] = 0.f;

    int rb = (tid >> 5) * 8;   // 0..56
    int cb = (tid & 31) * 4;   // 0..124

    for (int kc = 0; kc < 128; kc += 32) {
        // stage X: 64 rows x 32 k = 512 float4s, 2 per thread
#pragma unroll
        for (int l = 0; l < 2; ++l) {
            int idx = tid + l * 256;       // 0..511
            int r = idx >> 3;              // 0..63
            int q = (idx & 7) * 4;         // 0..28
            int gm = m0 + r;
            float4 v = make_float4(0.f, 0.f, 0.f, 0.f);
            if (gm < M) v = *(const float4*)(X + (size_t)gm * 128 + kc + q);
            *(float4*)&Xs[r][q] = v;
        }
        // stage W: 32 k x 128 j = 1024 float4s? no: 4096 floats = 1024 float4, 4 per thread
#pragma unroll
        for (int l = 0; l < 4; ++l) {
            int idx = tid + l * 256;       // 0..1023
            int k = idx >> 5;              // 0..31
            int j = (idx & 31) * 4;        // 0..124
            *(float4*)&Ws[k][j] = *(const float4*)(W + (size_t)(kc + k) * 128 + j);
        }
        __syncthreads();
#pragma unroll 8
        for (int k = 0; k < 32; ++k) {
            float4 wv = *(const float4*)&Ws[k][cb];
            float xr[8];
#pragma unroll
            for (int i = 0; i < 8; i++) xr[i] = Xs[rb + i][k];
#pragma unroll
            for (int i = 0; i < 8; i++) {
                acc[i][0] = fmaf(xr[i], wv.x, acc[i][0]);
                acc[i][1] = fmaf(xr[i], wv.y, acc[i][1]);
                acc[i][2] = fmaf(xr[i], wv.z, acc[i][2]);
                acc[i][3] = fmaf(xr[i], wv.w, acc[i][3]);
            }
        }
        __syncthreads();
    }

    float4 bias = *(const float4*)(bp + cb);
#pragma unroll
    for (int i = 0; i < 8; i++) {
        int gm = m0 + rb + i;
        if (gm < M) {
            size_t base = (size_t)gm * 256 + yb * 128 + cb;
            float4 v;
            v.x = acc[i][0] + bias.x;
            v.y = acc[i][1] + bias.y;
            v.z = acc[i][2] + bias.z;
            v.w = acc[i][3] + bias.w;
            if (accumulate) {
                float4 h = *(const float4*)(H + base);
                v.x += h.x;
                v.y += h.y;
                v.z += h.z;
                v.w += h.w;
            }
            *(float4*)(H + base) = v;
        }
    }
}

// ---------------- CSR gather aggregation + relu ----------------
__global__ __launch_bounds__(128) void agg_relu_k(const float* __restrict__ H,
                                                  const int* __restrict__ rowptr,
                                                  const int* __restrict__ adj,
                                                  float* __restrict__ Xo, int Nv) {
    int n = blockIdx.x;
    int j = threadIdx.x;
    float acc = H[(size_t)n * 256 + j];
    int s = rowptr[n], e = rowptr[n + 1];
    for (int t = s; t < e; ++t) {
        int nb = adj[t];
        acc += H[(size_t)nb * 256 + 128 + j];
    }
    Xo[(size_t)n * 128 + j] = fmaxf(acc, 0.f);
}

// ---------------- head: out = X @ off_w + off_b ----------------
__global__ __launch_bounds__(128) void final_out_k(const float* __restrict__ X,
                                                   const float* __restrict__ off_w,
                                                   const float* __restrict__ off_b,
                                                   float* __restrict__ out, int Nv) {
    __shared__ float s0[128], s1[128], s2[128];
    int n = blockIdx.x, k = threadIdx.x;
    float x = X[(size_t)n * 128 + k];
    s0[k] = x * off_w[k * 3 + 0];
    s1[k] = x * off_w[k * 3 + 1];
    s2[k] = x * off_w[k * 3 + 2];
    __syncthreads();
    for (int off = 64; off > 0; off >>= 1) {
        if (k < off) {
            s0[k] += s0[k + off];
            s1[k] += s1[k + off];
            s2[k] += s2[k + off];
        }
        __syncthreads();
    }
    if (k == 0) {
        out[n * 3 + 0] = s0[0] + off_b[0];
        out[n * 3 + 1] = s1[0] + off_b[1];
        out[n * 3 + 2] = s2[0] + off_b[2];
    }
}

extern "C" void kernel_launch(void* const* d_in, const int* in_sizes, int n_in, void* d_out,
                              int out_size, void* d_ws, size_t ws_size, hipStream_t stream) {
    const float* feat1 = (const float*)d_in[0];
    const float* feat2 = (const float*)d_in[1];
    const float* feat3 = (const float*)d_in[2];
    const float* feat4 = (const float*)d_in[3];
    const float* av = (const float*)d_in[4];
    const float* verts = (const float*)d_in[5];
    const float* image_enc = (const float*)d_in[6];
    const int* edges = (const int*)d_in[7];
    const float* bw = (const float*)d_in[8];
    const float* bb = (const float*)d_in[9];
    const float* g0w0 = (const float*)d_in[10];
    const float* g0b0 = (const float*)d_in[11];
    const float* g0w1 = (const float*)d_in[12];
    const float* g0b1 = (const float*)d_in[13];
    const float* gw0 = (const float*)d_in[14];
    const float* gb0 = (const float*)d_in[15];
    const float* gw1 = (const float*)d_in[16];
    const float* gb1 = (const float*)d_in[17];
    const float* off_w = (const float*)d_in[18];
    const float* off_b = (const float*)d_in[19];

    int B_ = in_sizes[6] / 256;       // 4
    int N_ = in_sizes[5] / 3;         // 40968
    int V_ = N_ / B_;                 // 10242
    int E_ = in_sizes[7] / 2;         // 122880

    char* wsb = (char*)d_ws;
    size_t off = 0;
    auto alloc = [&](size_t bytes) -> void* {
        void* p = (void*)(wsb + off);
        off += (bytes + 255) & ~(size_t)255;
        return p;
    };
    float* pp1 = (float*)alloc((size_t)B_ * 3136 * 128 * 4);
    float* pp2 = (float*)alloc((size_t)B_ * 784 * 128 * 4);
    float* pp3 = (float*)alloc((size_t)B_ * 196 * 128 * 4);
    float* pp4 = (float*)alloc((size_t)B_ * 49 * 128 * 4);
    float* XA = (float*)alloc((size_t)N_ * 128 * 4);
    float* XB = (float*)alloc((size_t)N_ * 128 * 4);
    float* Hb = (float*)alloc((size_t)N_ * 256 * 4);
    float* encp = (float*)alloc((size_t)2 * B_ * 128 * 4);
    int* deg = (int*)alloc((size_t)(N_ + 1) * 4);
    int* rowptr = (int*)alloc((size_t)(N_ + 1) * 4);
    int* cursor = (int*)alloc((size_t)N_ * 4);
    int* adj = (int*)alloc((size_t)2 * E_ * 4);

    // CSR build (edges fixed per call, rebuilt every call)
    hipMemsetAsync(deg, 0, (N_ + 1) * sizeof(int), stream);
    count_deg_k<<<ceil_div(E_, 256), 256, 0, stream>>>(edges, deg, E_);
    scan_k<<<1, 1024, 0, stream>>>(deg, rowptr, cursor, N_);
    fill_adj_k<<<ceil_div(E_, 256), 256, 0, stream>>>(edges, cursor, adj, E_);

    // per-batch enc projection for layer 0
    enc_proj_k<<<dim3(B_, 2), 128, 0, stream>>>(image_enc, g0w0, g0w1, encp, B_);

    // pixel projections (bilinear commutes with linear projection)
    gemm_proj_k<<<dim3(49, B_), 256, 0, stream>>>(feat1, bw + 0 * 128, pp1, 256, 3136);
    gemm_proj_k<<<dim3(13, B_), 256, 0, stream>>>(feat2, bw + 256 * 128, pp2, 512, 784);
    gemm_proj_k<<<dim3(4, B_), 256, 0, stream>>>(feat3, bw + 768 * 128, pp3, 1024, 196);
    gemm_proj_k<<<dim3(1, B_), 256, 0, stream>>>(feat4, bw + 1792 * 128, pp4, 2048, 49);

    // sample + bottleneck bias/relu -> XA ; layer0 pre-bias (verts + enc terms) -> Hb
    sample_bottleneck_k<<<N_, 128, 0, stream>>>(av, pp1, pp2, pp3, pp4, bb, verts, encp, g0w0,
                                                g0w1, XA, Hb, V_, B_);

    dim3 ggrid(ceil_div(N_, 64), 2);
    // layer 0 (accumulate pre-bias already in Hb)
    gemm_layer_k<<<ggrid, 256, 0, stream>>>(XA, g0w0, g0w1, g0b0, g0b1, Hb, N_, 1);
    agg_relu_k<<<N_, 128, 0, stream>>>(Hb, rowptr, adj, XB, N_);

    float* Xc = XB;
    float* Xn = XA;
    for (int i = 0; i < 7; ++i) {
        gemm_layer_k<<<ggrid, 256, 0, stream>>>(Xc, gw0 + (size_t)i * 16384,
                                                gw1 + (size_t)i * 16384, gb0 + i * 128,
                                                gb1 + i * 128, Hb, N_, 0);
        agg_relu_k<<<N_, 128, 0, stream>>>(Hb, rowptr, adj, Xn, N_);
        float* t = Xc;
        Xc = Xn;
        Xn = t;
    }

    final_out_k<<<N_, 128, 0, stream>>>(Xc, off_w, off_b, (float*)d_out, N_);
}

// Round 3
// 1033.771 us; speedup vs baseline: 4.8769x; 1.2475x over previous
//
#include <hip/hip_runtime.h>

static inline int ceil_div(int a, int b) { return (a + b - 1) / b; }

// ---------------- CSR build ----------------
__global__ __launch_bounds__(256) void count_deg_k(const int* __restrict__ edges,
                                                   int* __restrict__ deg, int E) {
    int e = blockIdx.x * blockDim.x + threadIdx.x;
    if (e < E) {
        atomicAdd(&deg[edges[2 * e]], 1);
        atomicAdd(&deg[edges[2 * e + 1]], 1);
    }
}

__global__ __launch_bounds__(1024) void scan_k(const int* __restrict__ deg,
                                               int* __restrict__ rowptr,
                                               int* __restrict__ cursor, int Nv) {
    __shared__ int s[1024];
    __shared__ int carry;
    int tid = threadIdx.x;
    if (tid == 0) carry = 0;
    __syncthreads();
    for (int base = 0; base < Nv; base += 1024) {
        int i = base + tid;
        int v = (i < Nv) ? deg[i] : 0;
        s[tid] = v;
        __syncthreads();
        for (int off = 1; off < 1024; off <<= 1) {
            int t = (tid >= off) ? s[tid - off] : 0;
            __syncthreads();
            if (tid >= off) s[tid] += t;
            __syncthreads();
        }
        int incl = s[tid];
        int total = s[1023];
        int excl = incl - v + carry;
        if (i < Nv) { rowptr[i] = excl; cursor[i] = excl; }
        __syncthreads();
        if (tid == 0) carry += total;
        __syncthreads();
    }
    if (tid == 0) rowptr[Nv] = carry;
}

__global__ __launch_bounds__(256) void fill_adj_k(const int* __restrict__ edges,
                                                  int* __restrict__ cursor,
                                                  int* __restrict__ adj, int E) {
    int e = blockIdx.x * blockDim.x + threadIdx.x;
    if (e < E) {
        int a = edges[2 * e], b = edges[2 * e + 1];
        adj[atomicAdd(&cursor[a], 1)] = b;
        adj[atomicAdd(&cursor[b], 1)] = a;
    }
}

// ---------------- enc @ g0_w*[131:387] (per-batch constant) ----------------
__global__ __launch_bounds__(128) void enc_proj_k(const float* __restrict__ enc,
                                                  const float* __restrict__ w0,
                                                  const float* __restrict__ w1,
                                                  float* __restrict__ out, int B_) {
    int b = blockIdx.x, sH = blockIdx.y, j = threadIdx.x;
    const float* w = sH ? w1 : w0;
    const float* eb = enc + b * 256;
    float acc = 0.f;
    for (int c = 0; c < 256; ++c) acc = fmaf(eb[c], w[(131 + c) * 128 + j], acc);
    out[(sH * B_ + b) * 128 + j] = acc;
}

// ---------------- pixel projection with K-split:
// pp[b][p][j] += sum_{c in chunk} fm[b][c][p] * W[c][j]
// grid: (ceil(HW/64), B, C/Cchunk). pp must be zeroed first.
__global__ __launch_bounds__(256) void gemm_proj_k(const float* __restrict__ fm,
                                                   const float* __restrict__ W,
                                                   float* __restrict__ pp, int C, int HW,
                                                   int Cchunk) {
    __shared__ float Xs[32][64];
    __shared__ float Ws[32][128];
    int tid = threadIdx.x;
    int p0 = blockIdx.x * 64;
    int b = blockIdx.y;
    int c0 = blockIdx.z * Cchunk;
    const float* fmb = fm + (size_t)b * C * HW;
    float acc[8][4];
#pragma unroll
    for (int i = 0; i < 8; i++)
#pragma unroll
        for (int j = 0; j < 4; j++) acc[i][j] = 0.f;

    bool vec_ok = ((HW & 3) == 0);
    for (int kc = c0; kc < c0 + Cchunk; kc += 32) {
        {
            int p4 = (tid & 15) * 4;
            int k0 = tid >> 4;  // 0..15
#pragma unroll
            for (int kk = 0; kk < 32; kk += 16) {
                int k = k0 + kk;
                const float* src = fmb + (size_t)(kc + k) * HW + p0 + p4;
                float4 v;
                if (vec_ok && (p0 + p4 + 3 < HW)) {
                    v = *(const float4*)src;
                } else {
                    v.x = (p0 + p4 + 0 < HW) ? src[0] : 0.f;
                    v.y = (p0 + p4 + 1 < HW) ? src[1] : 0.f;
                    v.z = (p0 + p4 + 2 < HW) ? src[2] : 0.f;
                    v.w = (p0 + p4 + 3 < HW) ? src[3] : 0.f;
                }
                *(float4*)&Xs[k][p4] = v;
            }
        }
        {
            int j4 = (tid & 31) * 4;
            int k0 = tid >> 5;  // 0..7
#pragma unroll
            for (int kk = 0; kk < 32; kk += 8) {
                int k = k0 + kk;
                *(float4*)&Ws[k][j4] = *(const float4*)(W + (size_t)(kc + k) * 128 + j4);
            }
        }
        __syncthreads();
        int rb = (tid >> 5) * 8;
        int cb = (tid & 31) * 4;
#pragma unroll 8
        for (int k = 0; k < 32; ++k) {
            float xr[8], wc[4];
#pragma unroll
            for (int i = 0; i < 8; i++) xr[i] = Xs[k][rb + i];
#pragma unroll
            for (int j = 0; j < 4; j++) wc[j] = Ws[k][cb + j];
#pragma unroll
            for (int i = 0; i < 8; i++)
#pragma unroll
                for (int j = 0; j < 4; j++) acc[i][j] = fmaf(xr[i], wc[j], acc[i][j]);
        }
        __syncthreads();
    }
    int rb = (tid >> 5) * 8;
    int cb = (tid & 31) * 4;
#pragma unroll
    for (int i = 0; i < 8; i++) {
        int p = p0 + rb + i;
        if (p < HW) {
            float* dst = pp + ((size_t)b * HW + p) * 128 + cb;
            if (gridDim.z == 1) {
                *(float4*)dst = make_float4(acc[i][0], acc[i][1], acc[i][2], acc[i][3]);
            } else {
                atomicAdd(dst + 0, acc[i][0]);
                atomicAdd(dst + 1, acc[i][1]);
                atomicAdd(dst + 2, acc[i][2]);
                atomicAdd(dst + 3, acc[i][3]);
            }
        }
    }
}

// ---------------- bilinear sample in projected space + bottleneck bias/relu + layer0 pre-bias ----------------
__device__ __forceinline__ float sample_level(const float* __restrict__ pp, int Hh, int Ww,
                                              float gx, float gy, int j) {
    float x = (gx + 1.f) * 0.5f * (float)(Ww - 1);
    float y = (gy + 1.f) * 0.5f * (float)(Hh - 1);
    float x0f = floorf(x), y0f = floorf(y);
    float wx1 = x - x0f, wy1 = y - y0f;
    float wx0 = 1.f - wx1, wy0 = 1.f - wy1;
    int x0 = (int)fminf(fmaxf(x0f, 0.f), (float)(Ww - 1));
    int x1 = (int)fminf(fmaxf(x0f + 1.f, 0.f), (float)(Ww - 1));
    int y0 = (int)fminf(fmaxf(y0f, 0.f), (float)(Hh - 1));
    int y1 = (int)fminf(fmaxf(y0f + 1.f, 0.f), (float)(Hh - 1));
    const float* r00 = pp + (size_t)(y0 * Ww + x0) * 128;
    const float* r01 = pp + (size_t)(y0 * Ww + x1) * 128;
    const float* r10 = pp + (size_t)(y1 * Ww + x0) * 128;
    const float* r11 = pp + (size_t)(y1 * Ww + x1) * 128;
    return wy0 * (wx0 * r00[j] + wx1 * r01[j]) + wy1 * (wx0 * r10[j] + wx1 * r11[j]);
}

__global__ __launch_bounds__(128) void sample_bottleneck_k(
    const float* __restrict__ av, const float* __restrict__ pp1, const float* __restrict__ pp2,
    const float* __restrict__ pp3, const float* __restrict__ pp4, const float* __restrict__ bb,
    const float* __restrict__ verts, const float* __restrict__ encp,
    const float* __restrict__ g0w0, const float* __restrict__ g0w1, float* __restrict__ X,
    float* __restrict__ H, int V_, int B_) {
    int n = blockIdx.x, j = threadIdx.x;
    int b = n / V_;
    float gx = av[(size_t)n * 3 + 0];
    float gy = av[(size_t)n * 3 + 1];
    float acc = bb[j];
    acc += sample_level(pp1 + (size_t)b * 3136 * 128, 56, 56, gx, gy, j);
    acc += sample_level(pp2 + (size_t)b * 784 * 128, 28, 28, gx, gy, j);
    acc += sample_level(pp3 + (size_t)b * 196 * 128, 14, 14, gx, gy, j);
    acc += sample_level(pp4 + (size_t)b * 49 * 128, 7, 7, gx, gy, j);
    X[(size_t)n * 128 + j] = fmaxf(acc, 0.f);
    float v0 = verts[n * 3 + 0], v1 = verts[n * 3 + 1], v2 = verts[n * 3 + 2];
    H[(size_t)n * 256 + j] = encp[(0 * B_ + b) * 128 + j] + v0 * g0w0[128 * 128 + j] +
                             v1 * g0w0[129 * 128 + j] + v2 * g0w0[130 * 128 + j];
    H[(size_t)n * 256 + 128 + j] = encp[(1 * B_ + b) * 128 + j] + v0 * g0w1[128 * 128 + j] +
                                   v1 * g0w1[129 * 128 + j] + v2 * g0w1[130 * 128 + j];
}

// ---------------- layer GEMM ----------------
__global__ __launch_bounds__(256, 4) void gemm_layer_k(const float* __restrict__ X,
                                                       const float* __restrict__ W0,
                                                       const float* __restrict__ W1,
                                                       const float* __restrict__ b0,
                                                       const float* __restrict__ b1,
                                                       float* __restrict__ H, int M,
                                                       int accumulate) {
    __shared__ float Xs[64][36];   // K-chunk 32, pad to 36
    __shared__ float Ws[32][128];
    int tid = threadIdx.x;
    int m0 = blockIdx.x * 64;
    int yb = blockIdx.y;
    const float* W = yb ? W1 : W0;
    const float* bp = yb ? b1 : b0;

    float acc[8][4];
#pragma unroll
    for (int i = 0; i < 8; i++)
#pragma unroll
        for (int j = 0; j < 4; j++) acc[i][j] = 0.f;

    int rb = (tid >> 5) * 8;   // 0..56
    int cb = (tid & 31) * 4;   // 0..124

    for (int kc = 0; kc < 128; kc += 32) {
#pragma unroll
        for (int l = 0; l < 2; ++l) {
            int idx = tid + l * 256;       // 0..511
            int r = idx >> 3;              // 0..63
            int q = (idx & 7) * 4;         // 0..28
            int gm = m0 + r;
            float4 v = make_float4(0.f, 0.f, 0.f, 0.f);
            if (gm < M) v = *(const float4*)(X + (size_t)gm * 128 + kc + q);
            *(float4*)&Xs[r][q] = v;
        }
#pragma unroll
        for (int l = 0; l < 4; ++l) {
            int idx = tid + l * 256;       // 0..1023
            int k = idx >> 5;              // 0..31
            int j = (idx & 31) * 4;        // 0..124
            *(float4*)&Ws[k][j] = *(const float4*)(W + (size_t)(kc + k) * 128 + j);
        }
        __syncthreads();
#pragma unroll 8
        for (int k = 0; k < 32; ++k) {
            float4 wv = *(const float4*)&Ws[k][cb];
            float xr[8];
#pragma unroll
            for (int i = 0; i < 8; i++) xr[i] = Xs[rb + i][k];
#pragma unroll
            for (int i = 0; i < 8; i++) {
                acc[i][0] = fmaf(xr[i], wv.x, acc[i][0]);
                acc[i][1] = fmaf(xr[i], wv.y, acc[i][1]);
                acc[i][2] = fmaf(xr[i], wv.z, acc[i][2]);
                acc[i][3] = fmaf(xr[i], wv.w, acc[i][3]);
            }
        }
        __syncthreads();
    }

    float4 bias = *(const float4*)(bp + cb);
#pragma unroll
    for (int i = 0; i < 8; i++) {
        int gm = m0 + rb + i;
        if (gm < M) {
            size_t base = (size_t)gm * 256 + yb * 128 + cb;
            float4 v;
            v.x = acc[i][0] + bias.x;
            v.y = acc[i][1] + bias.y;
            v.z = acc[i][2] + bias.z;
            v.w = acc[i][3] + bias.w;
            if (accumulate) {
                float4 h = *(const float4*)(H + base);
                v.x += h.x;
                v.y += h.y;
                v.z += h.z;
                v.w += h.w;
            }
            *(float4*)(H + base) = v;
        }
    }
}

// ---------------- CSR gather aggregation + relu ----------------
__global__ __launch_bounds__(128) void agg_relu_k(const float* __restrict__ H,
                                                  const int* __restrict__ rowptr,
                                                  const int* __restrict__ adj,
                                                  float* __restrict__ Xo, int Nv) {
    int n = blockIdx.x;
    int j = threadIdx.x;
    float acc = H[(size_t)n * 256 + j];
    int s = rowptr[n], e = rowptr[n + 1];
    for (int t = s; t < e; ++t) {
        int nb = adj[t];
        acc += H[(size_t)nb * 256 + 128 + j];
    }
    Xo[(size_t)n * 128 + j] = fmaxf(acc, 0.f);
}

// ---------------- head: out = X @ off_w + off_b ----------------
__global__ __launch_bounds__(128) void final_out_k(const float* __restrict__ X,
                                                   const float* __restrict__ off_w,
                                                   const float* __restrict__ off_b,
                                                   float* __restrict__ out, int Nv) {
    __shared__ float s0[128], s1[128], s2[128];
    int n = blockIdx.x, k = threadIdx.x;
    float x = X[(size_t)n * 128 + k];
    s0[k] = x * off_w[k * 3 + 0];
    s1[k] = x * off_w[k * 3 + 1];
    s2[k] = x * off_w[k * 3 + 2];
    __syncthreads();
    for (int off = 64; off > 0; off >>= 1) {
        if (k < off) {
            s0[k] += s0[k + off];
            s1[k] += s1[k + off];
            s2[k] += s2[k + off];
        }
        __syncthreads();
    }
    if (k == 0) {
        out[n * 3 + 0] = s0[0] + off_b[0];
        out[n * 3 + 1] = s1[0] + off_b[1];
        out[n * 3 + 2] = s2[0] + off_b[2];
    }
}

extern "C" void kernel_launch(void* const* d_in, const int* in_sizes, int n_in, void* d_out,
                              int out_size, void* d_ws, size_t ws_size, hipStream_t stream) {
    const float* feat1 = (const float*)d_in[0];
    const float* feat2 = (const float*)d_in[1];
    const float* feat3 = (const float*)d_in[2];
    const float* feat4 = (const float*)d_in[3];
    const float* av = (const float*)d_in[4];
    const float* verts = (const float*)d_in[5];
    const float* image_enc = (const float*)d_in[6];
    const int* edges = (const int*)d_in[7];
    const float* bw = (const float*)d_in[8];
    const float* bb = (const float*)d_in[9];
    const float* g0w0 = (const float*)d_in[10];
    const float* g0b0 = (const float*)d_in[11];
    const float* g0w1 = (const float*)d_in[12];
    const float* g0b1 = (const float*)d_in[13];
    const float* gw0 = (const float*)d_in[14];
    const float* gb0 = (const float*)d_in[15];
    const float* gw1 = (const float*)d_in[16];
    const float* gb1 = (const float*)d_in[17];
    const float* off_w = (const float*)d_in[18];
    const float* off_b = (const float*)d_in[19];

    int B_ = in_sizes[6] / 256;       // 4
    int N_ = in_sizes[5] / 3;         // 40968
    int V_ = N_ / B_;                 // 10242
    int E_ = in_sizes[7] / 2;         // 122880

    char* wsb = (char*)d_ws;
    size_t off = 0;
    auto alloc = [&](size_t bytes) -> void* {
        void* p = (void*)(wsb + off);
        off += (bytes + 255) & ~(size_t)255;
        return p;
    };
    float* pp1 = (float*)alloc((size_t)B_ * 3136 * 128 * 4);
    float* pp2 = (float*)alloc((size_t)B_ * 784 * 128 * 4);
    float* pp3 = (float*)alloc((size_t)B_ * 196 * 128 * 4);
    float* pp4 = (float*)alloc((size_t)B_ * 49 * 128 * 4);
    float* XA = (float*)alloc((size_t)N_ * 128 * 4);
    float* XB = (float*)alloc((size_t)N_ * 128 * 4);
    float* Hb = (float*)alloc((size_t)N_ * 256 * 4);
    float* encp = (float*)alloc((size_t)2 * B_ * 128 * 4);
    int* deg = (int*)alloc((size_t)(N_ + 1) * 4);
    int* rowptr = (int*)alloc((size_t)(N_ + 1) * 4);
    int* cursor = (int*)alloc((size_t)N_ * 4);
    int* adj = (int*)alloc((size_t)2 * E_ * 4);

    // zero the K-split accumulation buffers (pp1..pp4 are contiguous)
    size_t pp_bytes = ((size_t)B_ * (3136 + 784 + 196 + 49) * 128) * 4;
    hipMemsetAsync(pp1, 0, pp_bytes, stream);

    // CSR build (edges fixed per call, rebuilt every call)
    hipMemsetAsync(deg, 0, (N_ + 1) * sizeof(int), stream);
    count_deg_k<<<ceil_div(E_, 256), 256, 0, stream>>>(edges, deg, E_);
    scan_k<<<1, 1024, 0, stream>>>(deg, rowptr, cursor, N_);
    fill_adj_k<<<ceil_div(E_, 256), 256, 0, stream>>>(edges, cursor, adj, E_);

    // per-batch enc projection for layer 0
    enc_proj_k<<<dim3(B_, 2), 128, 0, stream>>>(image_enc, g0w0, g0w1, encp, B_);

    // pixel projections (bilinear commutes with linear projection), K-split for parallelism
    gemm_proj_k<<<dim3(49, B_, 2), 256, 0, stream>>>(feat1, bw + 0 * 128, pp1, 256, 3136, 128);
    gemm_proj_k<<<dim3(13, B_, 4), 256, 0, stream>>>(feat2, bw + 256 * 128, pp2, 512, 784, 128);
    gemm_proj_k<<<dim3(4, B_, 16), 256, 0, stream>>>(feat3, bw + 768 * 128, pp3, 1024, 196, 64);
    gemm_proj_k<<<dim3(1, B_, 32), 256, 0, stream>>>(feat4, bw + 1792 * 128, pp4, 2048, 49, 64);

    // sample + bottleneck bias/relu -> XA ; layer0 pre-bias (verts + enc terms) -> Hb
    sample_bottleneck_k<<<N_, 128, 0, stream>>>(av, pp1, pp2, pp3, pp4, bb, verts, encp, g0w0,
                                                g0w1, XA, Hb, V_, B_);

    dim3 ggrid(ceil_div(N_, 64), 2);
    // layer 0 (accumulate pre-bias already in Hb)
    gemm_layer_k<<<ggrid, 256, 0, stream>>>(XA, g0w0, g0w1, g0b0, g0b1, Hb, N_, 1);
    agg_relu_k<<<N_, 128, 0, stream>>>(Hb, rowptr, adj, XB, N_);

    float* Xc = XB;
    float* Xn = XA;
    for (int i = 0; i < 7; ++i) {
        gemm_layer_k<<<ggrid, 256, 0, stream>>>(Xc, gw0 + (size_t)i * 16384,
                                                gw1 + (size_t)i * 16384, gb0 + i * 128,
                                                gb1 + i * 128, Hb, N_, 0);
        agg_relu_k<<<N_, 128, 0, stream>>>(Hb, rowptr, adj, Xn, N_);
        float* t = Xc;
        Xc = Xn;
        Xn = t;
    }

    final_out_k<<<N_, 128, 0, stream>>>(Xc, off_w, off_b, (float*)d_out, N_);
}

// Round 4
// 761.900 us; speedup vs baseline: 6.6172x; 1.3568x over previous
//
#include <hip/hip_runtime.h>

static inline int ceil_div(int a, int b) { return (a + b - 1) / b; }

typedef __attribute__((ext_vector_type(8))) short short8;
typedef __attribute__((ext_vector_type(4))) float floatx4;

__device__ __forceinline__ unsigned short f2bf(float f) {
    unsigned int u = __float_as_uint(f);
    unsigned int r = (u + 0x7fffu + ((u >> 16) & 1u)) >> 16;
    return (unsigned short)r;
}
__device__ __forceinline__ float bf2f(unsigned short h) {
    return __uint_as_float(((unsigned int)h) << 16);
}

// ---------------- CSR build ----------------
__global__ __launch_bounds__(256) void count_deg_k(const int* __restrict__ edges,
                                                   int* __restrict__ deg, int E) {
    int e = blockIdx.x * blockDim.x + threadIdx.x;
    if (e < E) {
        atomicAdd(&deg[edges[2 * e]], 1);
        atomicAdd(&deg[edges[2 * e + 1]], 1);
    }
}

// hierarchical scan: phase 1 — per-block exclusive scan + block totals
__global__ __launch_bounds__(1024) void scan1_k(const int* __restrict__ deg,
                                                int* __restrict__ excl,
                                                int* __restrict__ bsum, int Nv) {
    __shared__ int s[1024];
    int tid = threadIdx.x;
    int i = blockIdx.x * 1024 + tid;
    int v = (i < Nv) ? deg[i] : 0;
    s[tid] = v;
    __syncthreads();
    for (int off = 1; off < 1024; off <<= 1) {
        int t = (tid >= off) ? s[tid - off] : 0;
        __syncthreads();
        if (tid >= off) s[tid] += t;
        __syncthreads();
    }
    if (i < Nv) excl[i] = s[tid] - v;
    if (tid == 1023) bsum[blockIdx.x] = s[1023];
}

// phase 2 — scan the (<=64) block totals
__global__ __launch_bounds__(64) void scan2_k(int* __restrict__ bsum, int nb) {
    __shared__ int s[64];
    int tid = threadIdx.x;
    int v = (tid < nb) ? bsum[tid] : 0;
    s[tid] = v;
    __syncthreads();
    for (int off = 1; off < 64; off <<= 1) {
        int t = (tid >= off) ? s[tid - off] : 0;
        __syncthreads();
        if (tid >= off) s[tid] += t;
        __syncthreads();
    }
    if (tid < nb) bsum[tid] = s[tid] - v;  // exclusive block offsets
}

// phase 3 — add offsets, emit rowptr + cursor
__global__ __launch_bounds__(1024) void scan3_k(const int* __restrict__ excl,
                                                const int* __restrict__ bsum,
                                                const int* __restrict__ deg,
                                                int* __restrict__ rowptr,
                                                int* __restrict__ cursor, int Nv) {
    int i = blockIdx.x * 1024 + threadIdx.x;
    if (i < Nv) {
        int val = excl[i] + bsum[blockIdx.x];
        rowptr[i] = val;
        cursor[i] = val;
        if (i == Nv - 1) rowptr[Nv] = val + deg[i];
    }
}

__global__ __launch_bounds__(256) void fill_adj_k(const int* __restrict__ edges,
                                                  int* __restrict__ cursor,
                                                  int* __restrict__ adj, int E) {
    int e = blockIdx.x * blockDim.x + threadIdx.x;
    if (e < E) {
        int a = edges[2 * e], b = edges[2 * e + 1];
        adj[atomicAdd(&cursor[a], 1)] = b;
        adj[atomicAdd(&cursor[b], 1)] = a;
    }
}

// ---------------- weight prep: fp32 [K][128] -> bf16 transposed [128 n][128 k] ----------------
// Wt layout: [8 layers][2 halves][128][128]
__global__ __launch_bounds__(256) void prep_w_k(const float* __restrict__ g0w0,
                                                const float* __restrict__ g0w1,
                                                const float* __restrict__ gw0,
                                                const float* __restrict__ gw1,
                                                unsigned short* __restrict__ Wt) {
    int lh = blockIdx.x;
    int l = lh >> 1, h = lh & 1;
    const float* src;
    if (l == 0) src = h ? g0w1 : g0w0;  // [387][128], rows 0..127 used
    else src = (h ? gw1 : gw0) + (size_t)(l - 1) * 16384;
    unsigned short* dst = Wt + (size_t)lh * 16384;
    for (int idx = threadIdx.x; idx < 16384; idx += 256) {
        int n = idx >> 7, k = idx & 127;
        dst[n * 128 + k] = f2bf(src[k * 128 + n]);
    }
}

// ---------------- enc @ g0_w*[131:387] (per-batch constant) ----------------
__global__ __launch_bounds__(128) void enc_proj_k(const float* __restrict__ enc,
                                                  const float* __restrict__ w0,
                                                  const float* __restrict__ w1,
                                                  float* __restrict__ out, int B_) {
    int b = blockIdx.x, sH = blockIdx.y, j = threadIdx.x;
    const float* w = sH ? w1 : w0;
    const float* eb = enc + b * 256;
    float acc = 0.f;
    for (int c = 0; c < 256; ++c) acc = fmaf(eb[c], w[(131 + c) * 128 + j], acc);
    out[(sH * B_ + b) * 128 + j] = acc;
}

// ---------------- pixel projection with K-split ----------------
__global__ __launch_bounds__(256) void gemm_proj_k(const float* __restrict__ fm,
                                                   const float* __restrict__ W,
                                                   float* __restrict__ pp, int C, int HW,
                                                   int Cchunk) {
    __shared__ float Xs[32][64];
    __shared__ float Ws[32][128];
    int tid = threadIdx.x;
    int p0 = blockIdx.x * 64;
    int b = blockIdx.y;
    int c0 = blockIdx.z * Cchunk;
    const float* fmb = fm + (size_t)b * C * HW;
    float acc[8][4];
#pragma unroll
    for (int i = 0; i < 8; i++)
#pragma unroll
        for (int j = 0; j < 4; j++) acc[i][j] = 0.f;

    bool vec_ok = ((HW & 3) == 0);
    for (int kc = c0; kc < c0 + Cchunk; kc += 32) {
        {
            int p4 = (tid & 15) * 4;
            int k0 = tid >> 4;
#pragma unroll
            for (int kk = 0; kk < 32; kk += 16) {
                int k = k0 + kk;
                const float* src = fmb + (size_t)(kc + k) * HW + p0 + p4;
                float4 v;
                if (vec_ok && (p0 + p4 + 3 < HW)) {
                    v = *(const float4*)src;
                } else {
                    v.x = (p0 + p4 + 0 < HW) ? src[0] : 0.f;
                    v.y = (p0 + p4 + 1 < HW) ? src[1] : 0.f;
                    v.z = (p0 + p4 + 2 < HW) ? src[2] : 0.f;
                    v.w = (p0 + p4 + 3 < HW) ? src[3] : 0.f;
                }
                *(float4*)&Xs[k][p4] = v;
            }
        }
        {
            int j4 = (tid & 31) * 4;
            int k0 = tid >> 5;
#pragma unroll
            for (int kk = 0; kk < 32; kk += 8) {
                int k = k0 + kk;
                *(float4*)&Ws[k][j4] = *(const float4*)(W + (size_t)(kc + k) * 128 + j4);
            }
        }
        __syncthreads();
        int rb = (tid >> 5) * 8;
        int cb = (tid & 31) * 4;
#pragma unroll 8
        for (int k = 0; k < 32; ++k) {
            float xr[8], wc[4];
#pragma unroll
            for (int i = 0; i < 8; i++) xr[i] = Xs[k][rb + i];
#pragma unroll
            for (int j = 0; j < 4; j++) wc[j] = Ws[k][cb + j];
#pragma unroll
            for (int i = 0; i < 8; i++)
#pragma unroll
                for (int j = 0; j < 4; j++) acc[i][j] = fmaf(xr[i], wc[j], acc[i][j]);
        }
        __syncthreads();
    }
    int rb = (tid >> 5) * 8;
    int cb = (tid & 31) * 4;
#pragma unroll
    for (int i = 0; i < 8; i++) {
        int p = p0 + rb + i;
        if (p < HW) {
            float* dst = pp + ((size_t)b * HW + p) * 128 + cb;
            if (gridDim.z == 1) {
                *(float4*)dst = make_float4(acc[i][0], acc[i][1], acc[i][2], acc[i][3]);
            } else {
                atomicAdd(dst + 0, acc[i][0]);
                atomicAdd(dst + 1, acc[i][1]);
                atomicAdd(dst + 2, acc[i][2]);
                atomicAdd(dst + 3, acc[i][3]);
            }
        }
    }
}

// ---------------- bilinear sample + bottleneck relu (bf16 X) + layer0 pre-bias (bf16 H) ----------------
__device__ __forceinline__ float sample_level(const float* __restrict__ pp, int Hh, int Ww,
                                              float gx, float gy, int j) {
    float x = (gx + 1.f) * 0.5f * (float)(Ww - 1);
    float y = (gy + 1.f) * 0.5f * (float)(Hh - 1);
    float x0f = floorf(x), y0f = floorf(y);
    float wx1 = x - x0f, wy1 = y - y0f;
    float wx0 = 1.f - wx1, wy0 = 1.f - wy1;
    int x0 = (int)fminf(fmaxf(x0f, 0.f), (float)(Ww - 1));
    int x1 = (int)fminf(fmaxf(x0f + 1.f, 0.f), (float)(Ww - 1));
    int y0 = (int)fminf(fmaxf(y0f, 0.f), (float)(Hh - 1));
    int y1 = (int)fminf(fmaxf(y0f + 1.f, 0.f), (float)(Hh - 1));
    const float* r00 = pp + (size_t)(y0 * Ww + x0) * 128;
    const float* r01 = pp + (size_t)(y0 * Ww + x1) * 128;
    const float* r10 = pp + (size_t)(y1 * Ww + x0) * 128;
    const float* r11 = pp + (size_t)(y1 * Ww + x1) * 128;
    return wy0 * (wx0 * r00[j] + wx1 * r01[j]) + wy1 * (wx0 * r10[j] + wx1 * r11[j]);
}

__global__ __launch_bounds__(128) void sample_bottleneck_k(
    const float* __restrict__ av, const float* __restrict__ pp1, const float* __restrict__ pp2,
    const float* __restrict__ pp3, const float* __restrict__ pp4, const float* __restrict__ bb,
    const float* __restrict__ verts, const float* __restrict__ encp,
    const float* __restrict__ g0w0, const float* __restrict__ g0w1,
    unsigned short* __restrict__ X, unsigned short* __restrict__ H, int V_, int B_) {
    int n = blockIdx.x, j = threadIdx.x;
    int b = n / V_;
    float gx = av[(size_t)n * 3 + 0];
    float gy = av[(size_t)n * 3 + 1];
    float acc = bb[j];
    acc += sample_level(pp1 + (size_t)b * 3136 * 128, 56, 56, gx, gy, j);
    acc += sample_level(pp2 + (size_t)b * 784 * 128, 28, 28, gx, gy, j);
    acc += sample_level(pp3 + (size_t)b * 196 * 128, 14, 14, gx, gy, j);
    acc += sample_level(pp4 + (size_t)b * 49 * 128, 7, 7, gx, gy, j);
    X[(size_t)n * 128 + j] = f2bf(fmaxf(acc, 0.f));
    float v0 = verts[n * 3 + 0], v1 = verts[n * 3 + 1], v2 = verts[n * 3 + 2];
    float h0 = encp[(0 * B_ + b) * 128 + j] + v0 * g0w0[128 * 128 + j] +
               v1 * g0w0[129 * 128 + j] + v2 * g0w0[130 * 128 + j];
    float h1 = encp[(1 * B_ + b) * 128 + j] + v0 * g0w1[128 * 128 + j] +
               v1 * g0w1[129 * 128 + j] + v2 * g0w1[130 * 128 + j];
    H[(size_t)n * 256 + j] = f2bf(h0);
    H[(size_t)n * 256 + 128 + j] = f2bf(h1);
}

// ---------------- MFMA layer GEMM ----------------
// Block: 128 rows x 128 cols (grid.y selects W0/W1 half). 4 waves; wave w does
// rows [w*32, w*32+32) x all 128 cols. K=128 staged whole in LDS (bf16),
// XOR-swizzled 16B chunks for conflict-free mfma fragment reads.
__global__ __launch_bounds__(256, 2) void gemm_layer_mfma_k(
    const unsigned short* __restrict__ X,   // [M][128] bf16
    const unsigned short* __restrict__ Wt,  // [2][128][128] bf16, n-major
    const float* __restrict__ b0, const float* __restrict__ b1,
    unsigned short* __restrict__ H,         // [M][256] bf16
    int M, int accumulate) {
    __shared__ unsigned short lds[32768];   // 64 KB: Xs [0,16384), Ws [16384,32768)
    unsigned short* Xs = lds;
    unsigned short* Ws = lds + 16384;

    int tid = threadIdx.x;
    int m0 = blockIdx.x * 128;
    int yb = blockIdx.y;
    const unsigned short* W = Wt + (size_t)yb * 16384;
    const float* bias = yb ? b1 : b0;

    // stage X and W (16B chunks, XOR swizzle on chunk index)
#pragma unroll
    for (int l = 0; l < 8; ++l) {
        int idx = tid + l * 256;      // 0..2047
        int r = idx >> 4;             // 0..127
        int c16 = idx & 15;           // 16B chunk
        int sw = (c16 ^ (r & 15)) * 8;
        short8 xv = {0, 0, 0, 0, 0, 0, 0, 0};
        int gm = m0 + r;
        if (gm < M) xv = *(const short8*)(X + (size_t)gm * 128 + c16 * 8);
        *(short8*)&Xs[r * 128 + sw] = xv;
        *(short8*)&Ws[r * 128 + sw] = *(const short8*)(W + r * 128 + c16 * 8);
    }
    __syncthreads();

    int wave = tid >> 6, lane = tid & 63;
    int row16 = lane & 15;
    int quad = lane >> 4;
    int wrow = wave * 32;

    floatx4 acc[2][8];
#pragma unroll
    for (int i = 0; i < 2; i++)
#pragma unroll
        for (int j = 0; j < 8; j++) acc[i][j] = (floatx4){0.f, 0.f, 0.f, 0.f};

#pragma unroll
    for (int ks = 0; ks < 4; ++ks) {
        int c0 = ks * 4 + quad;  // base 16B chunk for this lane's k-slice
        short8 a0 = *(short8*)&Xs[(wrow + row16) * 128 + (c0 ^ row16) * 8];
        short8 a1 = *(short8*)&Xs[(wrow + 16 + row16) * 128 + (c0 ^ row16) * 8];
#pragma unroll
        for (int nt = 0; nt < 8; ++nt) {
            short8 b = *(short8*)&Ws[(nt * 16 + row16) * 128 + (c0 ^ row16) * 8];
            acc[0][nt] = __builtin_amdgcn_mfma_f32_16x16x32_bf16(a0, b, acc[0][nt], 0, 0, 0);
            acc[1][nt] = __builtin_amdgcn_mfma_f32_16x16x32_bf16(a1, b, acc[1][nt], 0, 0, 0);
        }
    }
    __syncthreads();

    // epilogue: acc + bias -> Cs (bf16, pitch 136 for bank spread), then coalesced copy-out
    unsigned short* Cs = lds;  // 128*136*2 = 34816 B, fits
#pragma unroll
    for (int rt = 0; rt < 2; ++rt) {
#pragma unroll
        for (int nt = 0; nt < 8; ++nt) {
            int col = nt * 16 + row16;
            float bv = bias[col];
#pragma unroll
            for (int r = 0; r < 4; ++r) {
                int row = wrow + rt * 16 + quad * 4 + r;
                Cs[row * 136 + col] = f2bf(acc[rt][nt][r] + bv);
            }
        }
    }
    __syncthreads();

    int r = tid >> 1;
    int ch = (tid & 1) * 64;
    int gm = m0 + r;
    if (gm < M) {
        size_t gbase = (size_t)gm * 256 + yb * 128 + ch;
#pragma unroll
        for (int c = 0; c < 64; c += 8) {
            short8 v = *(short8*)&Cs[r * 136 + ch + c];
            if (accumulate) {
                short8 h = *(const short8*)(H + gbase + c);
#pragma unroll
                for (int e = 0; e < 8; ++e)
                    v[e] = (short)f2bf(bf2f((unsigned short)v[e]) + bf2f((unsigned short)h[e]));
            }
            *(short8*)(H + gbase + c) = v;
        }
    }
}

// ---------------- CSR gather aggregation + relu (bf16 in/out, fp32 accumulate) ----------------
// 256 threads = 4 waves; each wave handles one vertex; lane covers 2 cols.
__global__ __launch_bounds__(256) void agg_relu_k(const unsigned short* __restrict__ H,
                                                  const int* __restrict__ rowptr,
                                                  const int* __restrict__ adj,
                                                  unsigned short* __restrict__ Xo, int Nv) {
    int wave = threadIdx.x >> 6, lane = threadIdx.x & 63;
    int n = blockIdx.x * 4 + wave;
    if (n >= Nv) return;
    unsigned int u = *(const unsigned int*)(H + (size_t)n * 256 + 2 * lane);
    float a0 = bf2f((unsigned short)(u & 0xffff));
    float a1 = bf2f((unsigned short)(u >> 16));
    int s = rowptr[n], e = rowptr[n + 1];
    for (int t = s; t < e; ++t) {
        int nb = adj[t];
        unsigned int w = *(const unsigned int*)(H + (size_t)nb * 256 + 128 + 2 * lane);
        a0 += bf2f((unsigned short)(w & 0xffff));
        a1 += bf2f((unsigned short)(w >> 16));
    }
    unsigned int out = (unsigned int)f2bf(fmaxf(a0, 0.f)) |
                       ((unsigned int)f2bf(fmaxf(a1, 0.f)) << 16);
    *(unsigned int*)(Xo + (size_t)n * 128 + 2 * lane) = out;
}

// ---------------- head: out = X @ off_w + off_b (bf16 X) ----------------
__global__ __launch_bounds__(128) void final_out_k(const unsigned short* __restrict__ X,
                                                   const float* __restrict__ off_w,
                                                   const float* __restrict__ off_b,
                                                   float* __restrict__ out, int Nv) {
    __shared__ float s0[128], s1[128], s2[128];
    int n = blockIdx.x, k = threadIdx.x;
    float x = bf2f(X[(size_t)n * 128 + k]);
    s0[k] = x * off_w[k * 3 + 0];
    s1[k] = x * off_w[k * 3 + 1];
    s2[k] = x * off_w[k * 3 + 2];
    __syncthreads();
    for (int off = 64; off > 0; off >>= 1) {
        if (k < off) {
            s0[k] += s0[k + off];
            s1[k] += s1[k + off];
            s2[k] += s2[k + off];
        }
        __syncthreads();
    }
    if (k == 0) {
        out[n * 3 + 0] = s0[0] + off_b[0];
        out[n * 3 + 1] = s1[0] + off_b[1];
        out[n * 3 + 2] = s2[0] + off_b[2];
    }
}

extern "C" void kernel_launch(void* const* d_in, const int* in_sizes, int n_in, void* d_out,
                              int out_size, void* d_ws, size_t ws_size, hipStream_t stream) {
    const float* feat1 = (const float*)d_in[0];
    const float* feat2 = (const float*)d_in[1];
    const float* feat3 = (const float*)d_in[2];
    const float* feat4 = (const float*)d_in[3];
    const float* av = (const float*)d_in[4];
    const float* verts = (const float*)d_in[5];
    const float* image_enc = (const float*)d_in[6];
    const int* edges = (const int*)d_in[7];
    const float* bw = (const float*)d_in[8];
    const float* bb = (const float*)d_in[9];
    const float* g0w0 = (const float*)d_in[10];
    const float* g0b0 = (const float*)d_in[11];
    const float* g0w1 = (const float*)d_in[12];
    const float* g0b1 = (const float*)d_in[13];
    const float* gw0 = (const float*)d_in[14];
    const float* gb0 = (const float*)d_in[15];
    const float* gw1 = (const float*)d_in[16];
    const float* gb1 = (const float*)d_in[17];
    const float* off_w = (const float*)d_in[18];
    const float* off_b = (const float*)d_in[19];

    int B_ = in_sizes[6] / 256;  // 4
    int N_ = in_sizes[5] / 3;    // 40968
    int V_ = N_ / B_;            // 10242
    int E_ = in_sizes[7] / 2;    // 122880

    char* wsb = (char*)d_ws;
    size_t off = 0;
    auto alloc = [&](size_t bytes) -> void* {
        void* p = (void*)(wsb + off);
        off += (bytes + 255) & ~(size_t)255;
        return p;
    };
    float* pp1 = (float*)alloc((size_t)B_ * 3136 * 128 * 4);
    float* pp2 = (float*)alloc((size_t)B_ * 784 * 128 * 4);
    float* pp3 = (float*)alloc((size_t)B_ * 196 * 128 * 4);
    float* pp4 = (float*)alloc((size_t)B_ * 49 * 128 * 4);
    unsigned short* XA = (unsigned short*)alloc((size_t)N_ * 128 * 2);
    unsigned short* XB = (unsigned short*)alloc((size_t)N_ * 128 * 2);
    unsigned short* Hb = (unsigned short*)alloc((size_t)N_ * 256 * 2);
    unsigned short* Wt = (unsigned short*)alloc((size_t)8 * 2 * 128 * 128 * 2);
    float* encp = (float*)alloc((size_t)2 * B_ * 128 * 4);
    int* deg = (int*)alloc((size_t)(N_ + 1) * 4);
    int* rowptr = (int*)alloc((size_t)(N_ + 1) * 4);
    int* cursor = (int*)alloc((size_t)N_ * 4);
    int* excl = (int*)alloc((size_t)N_ * 4);
    int* bsum = (int*)alloc((size_t)64 * 4);
    int* adj = (int*)alloc((size_t)2 * E_ * 4);

    size_t pp_bytes = ((size_t)B_ * (3136 + 784 + 196 + 49) * 128) * 4;
    hipMemsetAsync(pp1, 0, pp_bytes, stream);

    // CSR build
    hipMemsetAsync(deg, 0, (N_ + 1) * sizeof(int), stream);
    count_deg_k<<<ceil_div(E_, 256), 256, 0, stream>>>(edges, deg, E_);
    int nb = ceil_div(N_, 1024);
    scan1_k<<<nb, 1024, 0, stream>>>(deg, excl, bsum, N_);
    scan2_k<<<1, 64, 0, stream>>>(bsum, nb);
    scan3_k<<<nb, 1024, 0, stream>>>(excl, bsum, deg, rowptr, cursor, N_);
    fill_adj_k<<<ceil_div(E_, 256), 256, 0, stream>>>(edges, cursor, adj, E_);

    // weight prep (bf16 transposed) + enc projection
    prep_w_k<<<16, 256, 0, stream>>>(g0w0, g0w1, gw0, gw1, Wt);
    enc_proj_k<<<dim3(B_, 2), 128, 0, stream>>>(image_enc, g0w0, g0w1, encp, B_);

    // pixel projections (bilinear commutes with linear projection), K-split
    gemm_proj_k<<<dim3(49, B_, 2), 256, 0, stream>>>(feat1, bw + 0 * 128, pp1, 256, 3136, 128);
    gemm_proj_k<<<dim3(13, B_, 4), 256, 0, stream>>>(feat2, bw + 256 * 128, pp2, 512, 784, 128);
    gemm_proj_k<<<dim3(4, B_, 16), 256, 0, stream>>>(feat3, bw + 768 * 128, pp3, 1024, 196, 64);
    gemm_proj_k<<<dim3(1, B_, 32), 256, 0, stream>>>(feat4, bw + 1792 * 128, pp4, 2048, 49, 64);

    // sample + bottleneck -> XA (bf16); layer0 pre-bias -> Hb (bf16)
    sample_bottleneck_k<<<N_, 128, 0, stream>>>(av, pp1, pp2, pp3, pp4, bb, verts, encp, g0w0,
                                                g0w1, XA, Hb, V_, B_);

    dim3 ggrid(ceil_div(N_, 128), 2);
    dim3 agrid(ceil_div(N_, 4));
    // layer 0 (accumulate pre-bias already in Hb)
    gemm_layer_mfma_k<<<ggrid, 256, 0, stream>>>(XA, Wt, g0b0, g0b1, Hb, N_, 1);
    agg_relu_k<<<agrid, 256, 0, stream>>>(Hb, rowptr, adj, XB, N_);

    unsigned short* Xc = XB;
    unsigned short* Xn = XA;
    for (int i = 0; i < 7; ++i) {
        gemm_layer_mfma_k<<<ggrid, 256, 0, stream>>>(Xc, Wt + (size_t)(i + 1) * 32768,
                                                     gb0 + i * 128, gb1 + i * 128, Hb, N_, 0);
        agg_relu_k<<<agrid, 256, 0, stream>>>(Hb, rowptr, adj, Xn, N_);
        unsigned short* t = Xc;
        Xc = Xn;
        Xn = t;
    }

    final_out_k<<<N_, 128, 0, stream>>>(Xc, off_w, off_b, (float*)d_out, N_);
}

// Round 5
// 683.806 us; speedup vs baseline: 7.3729x; 1.1142x over previous
//
#include <hip/hip_runtime.h>

static inline int ceil_div(int a, int b) { return (a + b - 1) / b; }

typedef __attribute__((ext_vector_type(8))) short short8;
typedef __attribute__((ext_vector_type(4))) float floatx4;

__device__ __forceinline__ unsigned short f2bf(float f) {
    unsigned int u = __float_as_uint(f);
    unsigned int r = (u + 0x7fffu + ((u >> 16) & 1u)) >> 16;
    return (unsigned short)r;
}
__device__ __forceinline__ float bf2f(unsigned short h) {
    return __uint_as_float(((unsigned int)h) << 16);
}

// ---------------- CSR build ----------------
__global__ __launch_bounds__(256) void count_deg_k(const int* __restrict__ edges,
                                                   int* __restrict__ deg, int E) {
    int e = blockIdx.x * blockDim.x + threadIdx.x;
    if (e < E) {
        atomicAdd(&deg[edges[2 * e]], 1);
        atomicAdd(&deg[edges[2 * e + 1]], 1);
    }
}

__global__ __launch_bounds__(1024) void scan1_k(const int* __restrict__ deg,
                                                int* __restrict__ excl,
                                                int* __restrict__ bsum, int Nv) {
    __shared__ int s[1024];
    int tid = threadIdx.x;
    int i = blockIdx.x * 1024 + tid;
    int v = (i < Nv) ? deg[i] : 0;
    s[tid] = v;
    __syncthreads();
    for (int off = 1; off < 1024; off <<= 1) {
        int t = (tid >= off) ? s[tid - off] : 0;
        __syncthreads();
        if (tid >= off) s[tid] += t;
        __syncthreads();
    }
    if (i < Nv) excl[i] = s[tid] - v;
    if (tid == 1023) bsum[blockIdx.x] = s[1023];
}

__global__ __launch_bounds__(64) void scan2_k(int* __restrict__ bsum, int nb) {
    __shared__ int s[64];
    int tid = threadIdx.x;
    int v = (tid < nb) ? bsum[tid] : 0;
    s[tid] = v;
    __syncthreads();
    for (int off = 1; off < 64; off <<= 1) {
        int t = (tid >= off) ? s[tid - off] : 0;
        __syncthreads();
        if (tid >= off) s[tid] += t;
        __syncthreads();
    }
    if (tid < nb) bsum[tid] = s[tid] - v;
}

__global__ __launch_bounds__(1024) void scan3_k(const int* __restrict__ excl,
                                                const int* __restrict__ bsum,
                                                const int* __restrict__ deg,
                                                int* __restrict__ rowptr,
                                                int* __restrict__ cursor, int Nv) {
    int i = blockIdx.x * 1024 + threadIdx.x;
    if (i < Nv) {
        int val = excl[i] + bsum[blockIdx.x];
        rowptr[i] = val;
        cursor[i] = val;
        if (i == Nv - 1) rowptr[Nv] = val + deg[i];
    }
}

__global__ __launch_bounds__(256) void fill_adj_k(const int* __restrict__ edges,
                                                  int* __restrict__ cursor,
                                                  int* __restrict__ adj, int E) {
    int e = blockIdx.x * blockDim.x + threadIdx.x;
    if (e < E) {
        int a = edges[2 * e], b = edges[2 * e + 1];
        adj[atomicAdd(&cursor[a], 1)] = b;
        adj[atomicAdd(&cursor[b], 1)] = a;
    }
}

// ---------------- weight prep: fp32 [K][128] -> bf16 transposed [128 n][128 k] ----------------
__global__ __launch_bounds__(256) void prep_w_k(const float* __restrict__ g0w0,
                                                const float* __restrict__ g0w1,
                                                const float* __restrict__ gw0,
                                                const float* __restrict__ gw1,
                                                unsigned short* __restrict__ Wt) {
    int lh = blockIdx.x;
    int l = lh >> 1, h = lh & 1;
    const float* src;
    if (l == 0) src = h ? g0w1 : g0w0;
    else src = (h ? gw1 : gw0) + (size_t)(l - 1) * 16384;
    unsigned short* dst = Wt + (size_t)lh * 16384;
    for (int idx = threadIdx.x; idx < 16384; idx += 256) {
        int n = idx >> 7, k = idx & 127;
        dst[n * 128 + k] = f2bf(src[k * 128 + n]);
    }
}

// ---------------- enc @ g0_w*[131:387] ----------------
__global__ __launch_bounds__(128) void enc_proj_k(const float* __restrict__ enc,
                                                  const float* __restrict__ w0,
                                                  const float* __restrict__ w1,
                                                  float* __restrict__ out, int B_) {
    int b = blockIdx.x, sH = blockIdx.y, j = threadIdx.x;
    const float* w = sH ? w1 : w0;
    const float* eb = enc + b * 256;
    float acc = 0.f;
    for (int c = 0; c < 256; ++c) acc = fmaf(eb[c], w[(131 + c) * 128 + j], acc);
    out[(sH * B_ + b) * 128 + j] = acc;
}

// ---------------- pixel projection, K-split -> disjoint partial buffers (no atomics) ----------------
// out[z][b*HW*128 + p*128 + j] = sum_{c in chunk z} fm[b][c][p] * W[c][j]
__global__ __launch_bounds__(256) void gemm_proj_k(const float* __restrict__ fm,
                                                   const float* __restrict__ W,
                                                   float* __restrict__ out, int C, int HW,
                                                   int Cchunk, int S) {
    __shared__ float Xs[32][64];
    __shared__ float Ws[32][128];
    int tid = threadIdx.x;
    int p0 = blockIdx.x * 64;
    int b = blockIdx.y;
    int c0 = blockIdx.z * Cchunk;
    const float* fmb = fm + (size_t)b * C * HW;
    float acc[8][4];
#pragma unroll
    for (int i = 0; i < 8; i++)
#pragma unroll
        for (int j = 0; j < 4; j++) acc[i][j] = 0.f;

    bool vec_ok = ((HW & 3) == 0);
    for (int kc = c0; kc < c0 + Cchunk; kc += 32) {
        {
            int p4 = (tid & 15) * 4;
            int k0 = tid >> 4;
#pragma unroll
            for (int kk = 0; kk < 32; kk += 16) {
                int k = k0 + kk;
                const float* src = fmb + (size_t)(kc + k) * HW + p0 + p4;
                float4 v;
                if (vec_ok && (p0 + p4 + 3 < HW)) {
                    v = *(const float4*)src;
                } else {
                    v.x = (p0 + p4 + 0 < HW) ? src[0] : 0.f;
                    v.y = (p0 + p4 + 1 < HW) ? src[1] : 0.f;
                    v.z = (p0 + p4 + 2 < HW) ? src[2] : 0.f;
                    v.w = (p0 + p4 + 3 < HW) ? src[3] : 0.f;
                }
                *(float4*)&Xs[k][p4] = v;
            }
        }
        {
            int j4 = (tid & 31) * 4;
            int k0 = tid >> 5;
#pragma unroll
            for (int kk = 0; kk < 32; kk += 8) {
                int k = k0 + kk;
                *(float4*)&Ws[k][j4] = *(const float4*)(W + (size_t)(kc + k) * 128 + j4);
            }
        }
        __syncthreads();
        int rb = (tid >> 5) * 8;
        int cb = (tid & 31) * 4;
#pragma unroll 8
        for (int k = 0; k < 32; ++k) {
            float xr[8], wc[4];
#pragma unroll
            for (int i = 0; i < 8; i++) xr[i] = Xs[k][rb + i];
#pragma unroll
            for (int j = 0; j < 4; j++) wc[j] = Ws[k][cb + j];
#pragma unroll
            for (int i = 0; i < 8; i++)
#pragma unroll
                for (int j = 0; j < 4; j++) acc[i][j] = fmaf(xr[i], wc[j], acc[i][j]);
        }
        __syncthreads();
    }
    int rb = (tid >> 5) * 8;
    int cb = (tid & 31) * 4;
    float* obase = out + (size_t)blockIdx.z * S;
#pragma unroll
    for (int i = 0; i < 8; i++) {
        int p = p0 + rb + i;
        if (p < HW) {
            *(float4*)(obase + ((size_t)b * HW + p) * 128 + cb) =
                make_float4(acc[i][0], acc[i][1], acc[i][2], acc[i][3]);
        }
    }
}

// ---------------- reduce partials for levels 2/3/4 ----------------
__global__ __launch_bounds__(256) void reduce_pp_k(const float* __restrict__ p2,
                                                   const float* __restrict__ p3,
                                                   const float* __restrict__ p4,
                                                   float* __restrict__ o2,
                                                   float* __restrict__ o3,
                                                   float* __restrict__ o4, int S2, int S3,
                                                   int S4) {
    int idx4 = blockIdx.x * 256 + threadIdx.x;
    int i = idx4 * 4;
    const float* src;
    float* dst;
    int S, z, base;
    if (i < S2) {
        src = p2; dst = o2; S = S2; z = 4; base = i;
    } else if (i < S2 + S3) {
        src = p3; dst = o3; S = S3; z = 8; base = i - S2;
    } else if (i < S2 + S3 + S4) {
        src = p4; dst = o4; S = S4; z = 16; base = i - S2 - S3;
    } else {
        return;
    }
    float4 a = *(const float4*)(src + base);
    for (int zz = 1; zz < z; ++zz) {
        float4 b = *(const float4*)(src + (size_t)zz * S + base);
        a.x += b.x; a.y += b.y; a.z += b.z; a.w += b.w;
    }
    *(float4*)(dst + base) = a;
}

// ---------------- bilinear sample + bottleneck relu (bf16 X) + layer0 pre-bias (bf16 H) ----------------
__device__ __forceinline__ float sample_level(const float* __restrict__ pp, int Hh, int Ww,
                                              float gx, float gy, int j) {
    float x = (gx + 1.f) * 0.5f * (float)(Ww - 1);
    float y = (gy + 1.f) * 0.5f * (float)(Hh - 1);
    float x0f = floorf(x), y0f = floorf(y);
    float wx1 = x - x0f, wy1 = y - y0f;
    float wx0 = 1.f - wx1, wy0 = 1.f - wy1;
    int x0 = (int)fminf(fmaxf(x0f, 0.f), (float)(Ww - 1));
    int x1 = (int)fminf(fmaxf(x0f + 1.f, 0.f), (float)(Ww - 1));
    int y0 = (int)fminf(fmaxf(y0f, 0.f), (float)(Hh - 1));
    int y1 = (int)fminf(fmaxf(y0f + 1.f, 0.f), (float)(Hh - 1));
    const float* r00 = pp + (size_t)(y0 * Ww + x0) * 128;
    const float* r01 = pp + (size_t)(y0 * Ww + x1) * 128;
    const float* r10 = pp + (size_t)(y1 * Ww + x0) * 128;
    const float* r11 = pp + (size_t)(y1 * Ww + x1) * 128;
    return wy0 * (wx0 * r00[j] + wx1 * r01[j]) + wy1 * (wx0 * r10[j] + wx1 * r11[j]);
}

__global__ __launch_bounds__(128) void sample_bottleneck_k(
    const float* __restrict__ av, const float* __restrict__ pp1, const float* __restrict__ pp2,
    const float* __restrict__ pp3, const float* __restrict__ pp4, const float* __restrict__ bb,
    const float* __restrict__ verts, const float* __restrict__ encp,
    const float* __restrict__ g0w0, const float* __restrict__ g0w1,
    unsigned short* __restrict__ X, unsigned short* __restrict__ H, int V_, int B_) {
    int n = blockIdx.x, j = threadIdx.x;
    int b = n / V_;
    float gx = av[(size_t)n * 3 + 0];
    float gy = av[(size_t)n * 3 + 1];
    float acc = bb[j];
    acc += sample_level(pp1 + (size_t)b * 3136 * 128, 56, 56, gx, gy, j);
    acc += sample_level(pp2 + (size_t)b * 784 * 128, 28, 28, gx, gy, j);
    acc += sample_level(pp3 + (size_t)b * 196 * 128, 14, 14, gx, gy, j);
    acc += sample_level(pp4 + (size_t)b * 49 * 128, 7, 7, gx, gy, j);
    X[(size_t)n * 128 + j] = f2bf(fmaxf(acc, 0.f));
    float v0 = verts[n * 3 + 0], v1 = verts[n * 3 + 1], v2 = verts[n * 3 + 2];
    float h0 = encp[(0 * B_ + b) * 128 + j] + v0 * g0w0[128 * 128 + j] +
               v1 * g0w0[129 * 128 + j] + v2 * g0w0[130 * 128 + j];
    float h1 = encp[(1 * B_ + b) * 128 + j] + v0 * g0w1[128 * 128 + j] +
               v1 * g0w1[129 * 128 + j] + v2 * g0w1[130 * 128 + j];
    H[(size_t)n * 256 + j] = f2bf(h0);
    H[(size_t)n * 256 + 128 + j] = f2bf(h1);
}

// ---------------- MFMA layer GEMM ----------------
__global__ __launch_bounds__(256, 2) void gemm_layer_mfma_k(
    const unsigned short* __restrict__ X, const unsigned short* __restrict__ Wt,
    const float* __restrict__ b0, const float* __restrict__ b1,
    unsigned short* __restrict__ H, int M, int accumulate) {
    __shared__ unsigned short lds[32768];
    unsigned short* Xs = lds;
    unsigned short* Ws = lds + 16384;

    int tid = threadIdx.x;
    int m0 = blockIdx.x * 128;
    int yb = blockIdx.y;
    const unsigned short* W = Wt + (size_t)yb * 16384;
    const float* bias = yb ? b1 : b0;

#pragma unroll
    for (int l = 0; l < 8; ++l) {
        int idx = tid + l * 256;
        int r = idx >> 4;
        int c16 = idx & 15;
        int sw = (c16 ^ (r & 15)) * 8;
        short8 xv = {0, 0, 0, 0, 0, 0, 0, 0};
        int gm = m0 + r;
        if (gm < M) xv = *(const short8*)(X + (size_t)gm * 128 + c16 * 8);
        *(short8*)&Xs[r * 128 + sw] = xv;
        *(short8*)&Ws[r * 128 + sw] = *(const short8*)(W + r * 128 + c16 * 8);
    }
    __syncthreads();

    int wave = tid >> 6, lane = tid & 63;
    int row16 = lane & 15;
    int quad = lane >> 4;
    int wrow = wave * 32;

    floatx4 acc[2][8];
#pragma unroll
    for (int i = 0; i < 2; i++)
#pragma unroll
        for (int j = 0; j < 8; j++) acc[i][j] = (floatx4){0.f, 0.f, 0.f, 0.f};

#pragma unroll
    for (int ks = 0; ks < 4; ++ks) {
        int c0 = ks * 4 + quad;
        short8 a0 = *(short8*)&Xs[(wrow + row16) * 128 + (c0 ^ row16) * 8];
        short8 a1 = *(short8*)&Xs[(wrow + 16 + row16) * 128 + (c0 ^ row16) * 8];
#pragma unroll
        for (int nt = 0; nt < 8; ++nt) {
            short8 b = *(short8*)&Ws[(nt * 16 + row16) * 128 + (c0 ^ row16) * 8];
            acc[0][nt] = __builtin_amdgcn_mfma_f32_16x16x32_bf16(a0, b, acc[0][nt], 0, 0, 0);
            acc[1][nt] = __builtin_amdgcn_mfma_f32_16x16x32_bf16(a1, b, acc[1][nt], 0, 0, 0);
        }
    }
    __syncthreads();

    unsigned short* Cs = lds;
#pragma unroll
    for (int rt = 0; rt < 2; ++rt) {
#pragma unroll
        for (int nt = 0; nt < 8; ++nt) {
            int col = nt * 16 + row16;
            float bv = bias[col];
#pragma unroll
            for (int r = 0; r < 4; ++r) {
                int row = wrow + rt * 16 + quad * 4 + r;
                Cs[row * 136 + col] = f2bf(acc[rt][nt][r] + bv);
            }
        }
    }
    __syncthreads();

    int r = tid >> 1;
    int ch = (tid & 1) * 64;
    int gm = m0 + r;
    if (gm < M) {
        size_t gbase = (size_t)gm * 256 + yb * 128 + ch;
#pragma unroll
        for (int c = 0; c < 64; c += 8) {
            short8 v = *(short8*)&Cs[r * 136 + ch + c];
            if (accumulate) {
                short8 h = *(const short8*)(H + gbase + c);
#pragma unroll
                for (int e = 0; e < 8; ++e)
                    v[e] = (short)f2bf(bf2f((unsigned short)v[e]) + bf2f((unsigned short)h[e]));
            }
            *(short8*)(H + gbase + c) = v;
        }
    }
}

// ---------------- CSR gather aggregation + relu; optionally fused output head ----------------
__global__ __launch_bounds__(256) void agg_relu_k(const unsigned short* __restrict__ H,
                                                  const int* __restrict__ rowptr,
                                                  const int* __restrict__ adj,
                                                  unsigned short* __restrict__ Xo,
                                                  const float* __restrict__ off_w,
                                                  const float* __restrict__ off_b,
                                                  float* __restrict__ out, int last, int Nv) {
    int wave = threadIdx.x >> 6, lane = threadIdx.x & 63;
    int n = blockIdx.x * 4 + wave;
    if (n >= Nv) return;
    unsigned int u = *(const unsigned int*)(H + (size_t)n * 256 + 2 * lane);
    float a0 = bf2f((unsigned short)(u & 0xffff));
    float a1 = bf2f((unsigned short)(u >> 16));
    int s = rowptr[n], e = rowptr[n + 1];
    for (int t = s; t < e; ++t) {
        int nb = adj[t];
        unsigned int w = *(const unsigned int*)(H + (size_t)nb * 256 + 128 + 2 * lane);
        a0 += bf2f((unsigned short)(w & 0xffff));
        a1 += bf2f((unsigned short)(w >> 16));
    }
    a0 = fmaxf(a0, 0.f);
    a1 = fmaxf(a1, 0.f);
    if (!last) {
        unsigned int o = (unsigned int)f2bf(a0) | ((unsigned int)f2bf(a1) << 16);
        *(unsigned int*)(Xo + (size_t)n * 128 + 2 * lane) = o;
    } else {
        int c0 = 2 * lane, c1 = 2 * lane + 1;
        float p0 = a0 * off_w[c0 * 3 + 0] + a1 * off_w[c1 * 3 + 0];
        float p1 = a0 * off_w[c0 * 3 + 1] + a1 * off_w[c1 * 3 + 1];
        float p2 = a0 * off_w[c0 * 3 + 2] + a1 * off_w[c1 * 3 + 2];
#pragma unroll
        for (int m = 1; m < 64; m <<= 1) {
            p0 += __shfl_xor(p0, m);
            p1 += __shfl_xor(p1, m);
            p2 += __shfl_xor(p2, m);
        }
        if (lane == 0) {
            out[n * 3 + 0] = p0 + off_b[0];
            out[n * 3 + 1] = p1 + off_b[1];
            out[n * 3 + 2] = p2 + off_b[2];
        }
    }
}

extern "C" void kernel_launch(void* const* d_in, const int* in_sizes, int n_in, void* d_out,
                              int out_size, void* d_ws, size_t ws_size, hipStream_t stream) {
    const float* feat1 = (const float*)d_in[0];
    const float* feat2 = (const float*)d_in[1];
    const float* feat3 = (const float*)d_in[2];
    const float* feat4 = (const float*)d_in[3];
    const float* av = (const float*)d_in[4];
    const float* verts = (const float*)d_in[5];
    const float* image_enc = (const float*)d_in[6];
    const int* edges = (const int*)d_in[7];
    const float* bw = (const float*)d_in[8];
    const float* bb = (const float*)d_in[9];
    const float* g0w0 = (const float*)d_in[10];
    const float* g0b0 = (const float*)d_in[11];
    const float* g0w1 = (const float*)d_in[12];
    const float* g0b1 = (const float*)d_in[13];
    const float* gw0 = (const float*)d_in[14];
    const float* gb0 = (const float*)d_in[15];
    const float* gw1 = (const float*)d_in[16];
    const float* gb1 = (const float*)d_in[17];
    const float* off_w = (const float*)d_in[18];
    const float* off_b = (const float*)d_in[19];

    int B_ = in_sizes[6] / 256;  // 4
    int N_ = in_sizes[5] / 3;    // 40968
    int V_ = N_ / B_;            // 10242
    int E_ = in_sizes[7] / 2;    // 122880

    char* wsb = (char*)d_ws;
    size_t off = 0;
    auto alloc = [&](size_t bytes) -> void* {
        void* p = (void*)(wsb + off);
        off += (bytes + 255) & ~(size_t)255;
        return p;
    };
    float* pp1 = (float*)alloc((size_t)B_ * 3136 * 128 * 4);
    float* pp2 = (float*)alloc((size_t)B_ * 784 * 128 * 4);
    float* pp3 = (float*)alloc((size_t)B_ * 196 * 128 * 4);
    float* pp4 = (float*)alloc((size_t)B_ * 49 * 128 * 4);
    unsigned short* XA = (unsigned short*)alloc((size_t)N_ * 128 * 2);
    unsigned short* XB = (unsigned short*)alloc((size_t)N_ * 128 * 2);
    unsigned short* Hb = (unsigned short*)alloc((size_t)N_ * 256 * 2);
    unsigned short* Wt = (unsigned short*)alloc((size_t)8 * 2 * 128 * 128 * 2);
    float* encp = (float*)alloc((size_t)2 * B_ * 128 * 4);
    int* deg = (int*)alloc((size_t)(N_ + 1) * 4);
    int* rowptr = (int*)alloc((size_t)(N_ + 1) * 4);
    int* cursor = (int*)alloc((size_t)N_ * 4);
    int* excl = (int*)alloc((size_t)N_ * 4);
    int* bsum = (int*)alloc((size_t)64 * 4);
    int* adj = (int*)alloc((size_t)2 * E_ * 4);

    // K-split partial buffers alias XA/XB (dead until sample_bottleneck_k)
    int S2 = B_ * 784 * 128;   // 401408
    int S3 = B_ * 196 * 128;   // 100352
    int S4 = B_ * 49 * 128;    // 25088
    float* pp2p = (float*)XA;                       // 4 * S2 * 4B = 6.42 MB  (XA: 10.49 MB)
    float* pp3p = (float*)XB;                       // 8 * S3 * 4B = 3.21 MB
    float* pp4p = (float*)((char*)XB + (size_t)8 * S3 * 4);  // 16 * S4 * 4B = 1.6 MB

    // CSR build
    hipMemsetAsync(deg, 0, (N_ + 1) * sizeof(int), stream);
    count_deg_k<<<ceil_div(E_, 256), 256, 0, stream>>>(edges, deg, E_);
    int nb = ceil_div(N_, 1024);
    scan1_k<<<nb, 1024, 0, stream>>>(deg, excl, bsum, N_);
    scan2_k<<<1, 64, 0, stream>>>(bsum, nb);
    scan3_k<<<nb, 1024, 0, stream>>>(excl, bsum, deg, rowptr, cursor, N_);
    fill_adj_k<<<ceil_div(E_, 256), 256, 0, stream>>>(edges, cursor, adj, E_);

    // weight prep (bf16 transposed) + enc projection
    prep_w_k<<<16, 256, 0, stream>>>(g0w0, g0w1, gw0, gw1, Wt);
    enc_proj_k<<<dim3(B_, 2), 128, 0, stream>>>(image_enc, g0w0, g0w1, encp, B_);

    // pixel projections: feat1 direct (no split); feat2/3/4 K-split to partials
    gemm_proj_k<<<dim3(49, B_, 1), 256, 0, stream>>>(feat1, bw + 0 * 128, pp1, 256, 3136, 256, 0);
    gemm_proj_k<<<dim3(13, B_, 4), 256, 0, stream>>>(feat2, bw + 256 * 128, pp2p, 512, 784, 128, S2);
    gemm_proj_k<<<dim3(4, B_, 8), 256, 0, stream>>>(feat3, bw + 768 * 128, pp3p, 1024, 196, 128, S3);
    gemm_proj_k<<<dim3(1, B_, 16), 256, 0, stream>>>(feat4, bw + 1792 * 128, pp4p, 2048, 49, 128, S4);
    reduce_pp_k<<<ceil_div((S2 + S3 + S4) / 4, 256), 256, 0, stream>>>(pp2p, pp3p, pp4p, pp2,
                                                                       pp3, pp4, S2, S3, S4);

    // sample + bottleneck -> XA (bf16); layer0 pre-bias -> Hb (bf16)
    sample_bottleneck_k<<<N_, 128, 0, stream>>>(av, pp1, pp2, pp3, pp4, bb, verts, encp, g0w0,
                                                g0w1, XA, Hb, V_, B_);

    dim3 ggrid(ceil_div(N_, 128), 2);
    dim3 agrid(ceil_div(N_, 4));
    gemm_layer_mfma_k<<<ggrid, 256, 0, stream>>>(XA, Wt, g0b0, g0b1, Hb, N_, 1);
    agg_relu_k<<<agrid, 256, 0, stream>>>(Hb, rowptr, adj, XB, off_w, off_b, (float*)d_out, 0, N_);

    unsigned short* Xc = XB;
    unsigned short* Xn = XA;
    for (int i = 0; i < 7; ++i) {
        gemm_layer_mfma_k<<<ggrid, 256, 0, stream>>>(Xc, Wt + (size_t)(i + 1) * 32768,
                                                     gb0 + i * 128, gb1 + i * 128, Hb, N_, 0);
        agg_relu_k<<<agrid, 256, 0, stream>>>(Hb, rowptr, adj, Xn, off_w, off_b, (float*)d_out,
                                              (i == 6) ? 1 : 0, N_);
        unsigned short* t = Xc;
        Xc = Xn;
        Xn = t;
    }
}